// Round 1
// baseline (411.165 us; speedup 1.0000x reference)
//
#include <hip/hip_runtime.h>
#include <cstdint>
#include <cmath>

// Causal self-attention: x[B,T,C] -> QKV proj -> flash attn -> out proj.
// B=4 T=2048 C=1024 H=16 DH=64. All matmuls in bf16 MFMA, fp32 accumulate.

#define Bb 4
#define Tt 2048
#define Cc 1024
#define Hh 16
#define DHd 64
#define Mm (Bb*Tt)   // 8192

typedef __attribute__((ext_vector_type(8))) short bf16x8;
typedef __attribute__((ext_vector_type(4))) short s16x4;
typedef __attribute__((ext_vector_type(4))) float f32x4;

__device__ __forceinline__ short f2bf(float f) {
  uint32_t u = __builtin_bit_cast(uint32_t, f);
  u = (u + 0x7fffu + ((u >> 16) & 1u)) >> 16;   // RNE
  return (short)(uint16_t)u;
}

// ---------------- fp32 -> bf16 convert (x4 vectorized) ----------------
__global__ void cvt_bf16(const float* __restrict__ in, short* __restrict__ out, int n4) {
  int i = blockIdx.x * blockDim.x + threadIdx.x;
  if (i >= n4) return;
  f32x4 v = reinterpret_cast<const f32x4*>(in)[i];
  s16x4 o;
  o.x = f2bf(v.x); o.y = f2bf(v.y); o.z = f2bf(v.z); o.w = f2bf(v.w);
  reinterpret_cast<s16x4*>(out)[i] = o;
}

// ---------------- 128x128 bf16 GEMM, C = A * Bt^T (both K-contiguous) ----------------
// MODE 0: QKV epilogue -> scatter to q/k/v [B,H,T,64] bf16, q scaled by 0.125
// MODE 1: plain fp32 store to Cout [M,N]
#define BK 32

template<int MODE>
__global__ __launch_bounds__(256) void gemm_bt(
    const short* __restrict__ A, const short* __restrict__ Bt, int K, int N,
    float* __restrict__ Cout,
    short* __restrict__ qb, short* __restrict__ kb, short* __restrict__ vb)
{
  __shared__ __align__(16) short As[128*BK];
  __shared__ __align__(16) short Bs[128*BK];
  const int tid = threadIdx.x;
  const int lane = tid & 63, wid = tid >> 6;
  const int wr = wid >> 1, wc = wid & 1;
  const int bm = blockIdx.y, bn = blockIdx.x;
  const int r16 = lane & 15, g = lane >> 4;

  f32x4 acc[4][4];
#pragma unroll
  for (int i = 0; i < 4; ++i)
#pragma unroll
    for (int j = 0; j < 4; ++j) acc[i][j] = (f32x4)0.0f;

  const int srow = lane >> 2;          // staging: row-within-chunk
  const int scol = (lane & 3) * 8;     // staging: k offset (8 bf16 = 16B)
  const int ch0 = wid * 2;

  const int nk = K / BK;
  for (int kt = 0; kt < nk; ++kt) {
    const int k0 = kt * BK;
#pragma unroll
    for (int c = 0; c < 2; ++c) {
      const int chunk = ch0 + c;                 // 0..7, wave-uniform
      const int row = chunk * 16 + srow;
      const short* ga = A  + (size_t)(bm*128 + row)*K + k0 + scol;
      const short* gb = Bt + (size_t)(bn*128 + row)*K + k0 + scol;
      __builtin_amdgcn_global_load_lds((const __attribute__((address_space(1))) void*)ga,
                                       (__attribute__((address_space(3))) void*)(&As[chunk*512]), 16, 0, 0);
      __builtin_amdgcn_global_load_lds((const __attribute__((address_space(1))) void*)gb,
                                       (__attribute__((address_space(3))) void*)(&Bs[chunk*512]), 16, 0, 0);
    }
    __syncthreads();

    bf16x8 af[4], bfv[4];
#pragma unroll
    for (int mi = 0; mi < 4; ++mi)
      af[mi] = *reinterpret_cast<const bf16x8*>(&As[(wr*64 + mi*16 + r16)*BK + g*8]);
#pragma unroll
    for (int ni = 0; ni < 4; ++ni)
      bfv[ni] = *reinterpret_cast<const bf16x8*>(&Bs[(wc*64 + ni*16 + r16)*BK + g*8]);
#pragma unroll
    for (int mi = 0; mi < 4; ++mi)
#pragma unroll
      for (int ni = 0; ni < 4; ++ni)
        acc[mi][ni] = __builtin_amdgcn_mfma_f32_16x16x32_bf16(af[mi], bfv[ni], acc[mi][ni], 0, 0, 0);
    __syncthreads();
  }

  // epilogue: D layout col = lane&15, row = (lane>>4)*4 + r
#pragma unroll
  for (int mi = 0; mi < 4; ++mi) {
    const int row0 = bm*128 + wr*64 + mi*16 + g*4;
#pragma unroll
    for (int ni = 0; ni < 4; ++ni) {
      const int col_g = bn*128 + wc*64 + ni*16 + r16;
#pragma unroll
      for (int r = 0; r < 4; ++r) {
        const float v = acc[mi][ni][r];
        const int rg = row0 + r;
        if (MODE == 1) {
          Cout[(size_t)rg * N + col_g] = v;
        } else {
          const int which = col_g >> 10;          // 0=q 1=k 2=v
          const int hd = col_g & 1023;
          const int h = hd >> 6, d = hd & 63;
          const int b = rg >> 11, t = rg & 2047;
          const size_t dst = (((size_t)(b*Hh + h)*Tt + t) << 6) + d;
          const short bv = f2bf(which == 0 ? v * 0.125f : v);
          short* p = (which == 0) ? qb : (which == 1) ? kb : vb;
          p[dst] = bv;
        }
      }
    }
  }
}

// ---------------- flash attention, causal + key mask ----------------
// grid: (T/64, B*H). 4 waves, each owns 16 q rows. KV tiles of 64 in LDS.
#define KPAD 72   // LDS row stride (shorts), padded vs 64

__global__ __launch_bounds__(256) void attn_fwd(
    const short* __restrict__ qbf, const short* __restrict__ kbf,
    const short* __restrict__ vbf, const int* __restrict__ am,
    short* __restrict__ ob)
{
  __shared__ __align__(16) short Ks[64*KPAD];
  __shared__ __align__(16) short Vs[64*KPAD];
  __shared__ __align__(16) short Ps[4*16*KPAD];
  const int tid = threadIdx.x;
  const int lane = tid & 63, wid = tid >> 6;
  const int r16 = lane & 15, g = lane >> 4;
  const int bh = blockIdx.y;
  const int b = bh >> 4, h = bh & 15;
  const int q0 = blockIdx.x * 64;

  // Q fragments (A-frag: row = lane&15, k = g*8+e), pre-scaled by 0.125
  const int qrow_a = q0 + wid*16 + r16;
  const short* qbase = qbf + ((size_t)bh*Tt + qrow_a)*DHd;
  const bf16x8 qf0 = *reinterpret_cast<const bf16x8*>(qbase + g*8);
  const bf16x8 qf1 = *reinterpret_cast<const bf16x8*>(qbase + 32 + g*8);

  f32x4 o[4];
  float mrow[4], lrow[4];
#pragma unroll
  for (int i = 0; i < 4; ++i) { o[i] = (f32x4)0.0f; mrow[i] = -INFINITY; lrow[i] = 0.0f; }

  short* Pw = &Ps[wid * 16 * KPAD];
  const int nkv = blockIdx.x + 1;

  for (int kv = 0; kv < nkv; ++kv) {
    const int kv0 = kv * 64;
    // stage K,V tiles (64 rows x 64 bf16), 2 chunks of 16B per thread each
#pragma unroll
    for (int c = 0; c < 2; ++c) {
      const int idx = tid + c*256;          // 0..511
      const int row = idx >> 3, cc = idx & 7;
      const size_t gofs = ((size_t)bh*Tt + kv0 + row)*DHd + cc*8;
      *reinterpret_cast<bf16x8*>(&Ks[row*KPAD + cc*8]) = *reinterpret_cast<const bf16x8*>(kbf + gofs);
      *reinterpret_cast<bf16x8*>(&Vs[row*KPAD + cc*8]) = *reinterpret_cast<const bf16x8*>(vbf + gofs);
    }
    __syncthreads();

    // S = (Q/8) K^T   [16 q x 64 k] per wave, 4 tiles of 16 cols
    f32x4 s[4];
#pragma unroll
    for (int kt = 0; kt < 4; ++kt) {
      const bf16x8 k0 = *reinterpret_cast<const bf16x8*>(&Ks[(kt*16 + r16)*KPAD + g*8]);
      const bf16x8 k1 = *reinterpret_cast<const bf16x8*>(&Ks[(kt*16 + r16)*KPAD + 32 + g*8]);
      f32x4 t = (f32x4)0.0f;
      t = __builtin_amdgcn_mfma_f32_16x16x32_bf16(qf0, k0, t, 0, 0, 0);
      t = __builtin_amdgcn_mfma_f32_16x16x32_bf16(qf1, k1, t, 0, 0, 0);
      s[kt] = t;
    }

    // masking: D layout -> col k = kv0+kt*16+r16, row q = q0+wid*16+g*4+r
    const int qrow_d = q0 + wid*16 + g*4;
#pragma unroll
    for (int kt = 0; kt < 4; ++kt) {
      const int kg = kv0 + kt*16 + r16;
      const bool mk = (am[b*Tt + kg] != 0);
#pragma unroll
      for (int r = 0; r < 4; ++r)
        if (!mk || kg > qrow_d + r) s[kt][r] = -1e30f;
    }

    // online softmax (row reduce across the 16 lanes of each g-group)
    float p[4][4];
#pragma unroll
    for (int r = 0; r < 4; ++r) {
      float mx = fmaxf(fmaxf(s[0][r], s[1][r]), fmaxf(s[2][r], s[3][r]));
      mx = fmaxf(mx, __shfl_xor(mx, 1));
      mx = fmaxf(mx, __shfl_xor(mx, 2));
      mx = fmaxf(mx, __shfl_xor(mx, 4));
      mx = fmaxf(mx, __shfl_xor(mx, 8));
      const float mnew = fmaxf(mrow[r], mx);
      const float alpha = __expf(mrow[r] - mnew);
      mrow[r] = mnew;
      float rs = 0.f;
#pragma unroll
      for (int kt = 0; kt < 4; ++kt) { const float e = __expf(s[kt][r] - mnew); p[kt][r] = e; rs += e; }
      rs += __shfl_xor(rs, 1); rs += __shfl_xor(rs, 2);
      rs += __shfl_xor(rs, 4); rs += __shfl_xor(rs, 8);
      lrow[r] = lrow[r]*alpha + rs;
#pragma unroll
      for (int dt = 0; dt < 4; ++dt) o[dt][r] *= alpha;
    }

    // P -> LDS (per-wave area, no cross-wave barrier needed)
#pragma unroll
    for (int kt = 0; kt < 4; ++kt)
#pragma unroll
      for (int r = 0; r < 4; ++r)
        Pw[(g*4 + r)*KPAD + kt*16 + r16] = f2bf(p[kt][r]);

    // O += P V   (A-frag from P in LDS; B-frag from V via scalar reads)
#pragma unroll
    for (int ks = 0; ks < 2; ++ks) {
      const bf16x8 pf = *reinterpret_cast<const bf16x8*>(&Pw[r16*KPAD + ks*32 + g*8]);
#pragma unroll
      for (int dt = 0; dt < 4; ++dt) {
        bf16x8 vf;
#pragma unroll
        for (int e = 0; e < 8; ++e)
          vf[e] = Vs[(ks*32 + g*8 + e)*KPAD + dt*16 + r16];
        o[dt] = __builtin_amdgcn_mfma_f32_16x16x32_bf16(pf, vf, o[dt], 0, 0, 0);
      }
    }
    __syncthreads();
  }

  // normalize + store to [B,T,C] bf16 (input of out-proj)
#pragma unroll
  for (int r = 0; r < 4; ++r) {
    const float inv = lrow[r] > 0.f ? 1.0f / lrow[r] : 0.f;
    const int trow = q0 + wid*16 + g*4 + r;
    const size_t base = ((size_t)(b*Tt + trow))*Cc + h*DHd;
#pragma unroll
    for (int dt = 0; dt < 4; ++dt)
      ob[base + dt*16 + r16] = f2bf(o[dt][r] * inv);
  }
}

// ---------------- launcher ----------------
extern "C" void kernel_launch(void* const* d_in, const int* in_sizes, int n_in,
                              void* d_out, int out_size, void* d_ws, size_t ws_size,
                              hipStream_t stream) {
  const float* x    = (const float*)d_in[0];
  const int*   am   = (const int*)d_in[1];
  const float* wqkv = (const float*)d_in[2];
  const float* wout = (const float*)d_in[3];
  float* out = (float*)d_out;

  const size_t mc = (size_t)Mm * Cc;        // 8,388,608
  short* ws    = (short*)d_ws;
  short* xb    = ws;                        // [8192,1024] bf16
  short* wqkvb = xb + mc;                   // [3072,1024]
  short* woutb = wqkvb + (size_t)3*Cc*Cc;   // [1024,1024]
  short* qbuf  = woutb + (size_t)Cc*Cc;     // [B,H,T,64]
  short* kbuf  = qbuf + mc;
  short* vbuf  = kbuf + mc;
  short* attnb = xb;                        // reuse x buffer after QKV GEMM

  cvt_bf16<<<(int)((mc/4 + 255)/256), 256, 0, stream>>>(x, xb, (int)(mc/4));
  cvt_bf16<<<(3*Cc*Cc/4 + 255)/256, 256, 0, stream>>>(wqkv, wqkvb, 3*Cc*Cc/4);
  cvt_bf16<<<(Cc*Cc/4 + 255)/256, 256, 0, stream>>>(wout, woutb, Cc*Cc/4);

  gemm_bt<0><<<dim3(3*Cc/128, Mm/128), 256, 0, stream>>>(
      xb, wqkvb, Cc, 3*Cc, nullptr, qbuf, kbuf, vbuf);

  attn_fwd<<<dim3(Tt/64, Bb*Hh), 256, 0, stream>>>(qbuf, kbuf, vbuf, am, attnb);

  gemm_bt<1><<<dim3(Cc/128, Mm/128), 256, 0, stream>>>(
      attnb, woutb, Cc, Cc, out, nullptr, nullptr, nullptr);
}

// Round 2
// 303.864 us; speedup vs baseline: 1.3531x; 1.3531x over previous
//
#include <hip/hip_runtime.h>
#include <cstdint>
#include <cmath>

// Causal self-attention: x[B,T,C] -> QKV proj -> flash attn -> out proj.
// B=4 T=2048 C=1024 H=16 DH=64. All matmuls in bf16 MFMA, fp32 accumulate.

#define Bb 4
#define Tt 2048
#define Cc 1024
#define Hh 16
#define DHd 64
#define Mm (Bb*Tt)   // 8192

typedef __attribute__((ext_vector_type(8))) short bf16x8;
typedef __attribute__((ext_vector_type(4))) short s16x4;
typedef __attribute__((ext_vector_type(4))) float f32x4;

__device__ __forceinline__ short f2bf(float f) {
  uint32_t u = __builtin_bit_cast(uint32_t, f);
  u = (u + 0x7fffu + ((u >> 16) & 1u)) >> 16;   // RNE
  return (short)(uint16_t)u;
}

// ---------------- fp32 -> bf16 convert (x4 vectorized) ----------------
__global__ void cvt_bf16(const float* __restrict__ in, short* __restrict__ out, int n4) {
  int i = blockIdx.x * blockDim.x + threadIdx.x;
  if (i >= n4) return;
  f32x4 v = reinterpret_cast<const f32x4*>(in)[i];
  s16x4 o;
  o.x = f2bf(v.x); o.y = f2bf(v.y); o.z = f2bf(v.z); o.w = f2bf(v.w);
  reinterpret_cast<s16x4*>(out)[i] = o;
}

// ---------------- 128x128 bf16 GEMM, C = A * Bt^T (both K-contiguous) ----------------
// MODE 0: QKV epilogue -> scatter to q [B,H,T,64] (scaled 0.125), k [B,H,T,64],
//         and V TRANSPOSED vt [B,H,64,T]
// MODE 1: plain fp32 store to Cout [M,N]
#define BK 32

template<int MODE>
__global__ __launch_bounds__(256) void gemm_bt(
    const short* __restrict__ A, const short* __restrict__ Bt, int K, int N,
    float* __restrict__ Cout,
    short* __restrict__ qb, short* __restrict__ kb, short* __restrict__ vtb)
{
  __shared__ __align__(16) short As[128*BK];
  __shared__ __align__(16) short Bs[128*BK];
  const int tid = threadIdx.x;
  const int lane = tid & 63, wid = tid >> 6;
  const int wr = wid >> 1, wc = wid & 1;
  const int bm = blockIdx.y, bn = blockIdx.x;
  const int r16 = lane & 15, g = lane >> 4;

  f32x4 acc[4][4];
#pragma unroll
  for (int i = 0; i < 4; ++i)
#pragma unroll
    for (int j = 0; j < 4; ++j) acc[i][j] = (f32x4)0.0f;

  const int srow = lane >> 2;          // staging: row-within-chunk
  const int scol = (lane & 3) * 8;     // staging: k offset (8 bf16 = 16B)
  const int ch0 = wid * 2;

  const int nk = K / BK;
  for (int kt = 0; kt < nk; ++kt) {
    const int k0 = kt * BK;
#pragma unroll
    for (int c = 0; c < 2; ++c) {
      const int chunk = ch0 + c;                 // 0..7, wave-uniform
      const int row = chunk * 16 + srow;
      const short* ga = A  + (size_t)(bm*128 + row)*K + k0 + scol;
      const short* gb = Bt + (size_t)(bn*128 + row)*K + k0 + scol;
      __builtin_amdgcn_global_load_lds((const __attribute__((address_space(1))) void*)ga,
                                       (__attribute__((address_space(3))) void*)(&As[chunk*512]), 16, 0, 0);
      __builtin_amdgcn_global_load_lds((const __attribute__((address_space(1))) void*)gb,
                                       (__attribute__((address_space(3))) void*)(&Bs[chunk*512]), 16, 0, 0);
    }
    __syncthreads();

    bf16x8 af[4], bfv[4];
#pragma unroll
    for (int mi = 0; mi < 4; ++mi)
      af[mi] = *reinterpret_cast<const bf16x8*>(&As[(wr*64 + mi*16 + r16)*BK + g*8]);
#pragma unroll
    for (int ni = 0; ni < 4; ++ni)
      bfv[ni] = *reinterpret_cast<const bf16x8*>(&Bs[(wc*64 + ni*16 + r16)*BK + g*8]);
#pragma unroll
    for (int mi = 0; mi < 4; ++mi)
#pragma unroll
      for (int ni = 0; ni < 4; ++ni)
        acc[mi][ni] = __builtin_amdgcn_mfma_f32_16x16x32_bf16(af[mi], bfv[ni], acc[mi][ni], 0, 0, 0);
    __syncthreads();
  }

  // epilogue: D layout col = lane&15, row = (lane>>4)*4 + r
#pragma unroll
  for (int mi = 0; mi < 4; ++mi) {
    const int row0 = bm*128 + wr*64 + mi*16 + g*4;
#pragma unroll
    for (int ni = 0; ni < 4; ++ni) {
      const int col_g = bn*128 + wc*64 + ni*16 + r16;
#pragma unroll
      for (int r = 0; r < 4; ++r) {
        const float v = acc[mi][ni][r];
        const int rg = row0 + r;
        if (MODE == 1) {
          Cout[(size_t)rg * N + col_g] = v;
        } else {
          const int which = col_g >> 10;          // 0=q 1=k 2=v
          const int hd = col_g & 1023;
          const int h = hd >> 6, d = hd & 63;
          const int b = rg >> 11, t = rg & 2047;
          const int bh = b*Hh + h;
          if (which == 0) {
            qb[(((size_t)bh*Tt + t) << 6) + d] = f2bf(v * 0.125f);
          } else if (which == 1) {
            kb[(((size_t)bh*Tt + t) << 6) + d] = f2bf(v);
          } else {
            vtb[((size_t)bh*DHd + d)*Tt + t] = f2bf(v);   // transposed
          }
        }
      }
    }
  }
}

// ---------------- flash attention, causal + key mask ----------------
// grid: (B*H=64, T/128=16). 4 waves; each wave owns 32 q rows (2 m-frags).
// KV tiles of 64 in LDS; V staged from transposed vt buffer.
#define KPAD 72   // LDS row stride (shorts)

__global__ __launch_bounds__(256) void attn_fwd(
    const short* __restrict__ qbf, const short* __restrict__ kbf,
    const short* __restrict__ vtb, const int* __restrict__ am,
    short* __restrict__ ob)
{
  __shared__ __align__(16) short Ks[64*KPAD];
  __shared__ __align__(16) short Vts[64*KPAD];   // transposed V tile [d=64][k=64]
  __shared__ __align__(16) short Ps[4*32*KPAD];
  const int tid = threadIdx.x;
  const int lane = tid & 63, wid = tid >> 6;
  const int r16 = lane & 15, g = lane >> 4;
  const int bh = blockIdx.x;
  const int b = bh >> 4, h = bh & 15;
  // balanced qi permutation: each set {y, y+4, y+8, y+12} sums to 30; heavy first
  const int grp = blockIdx.y >> 2, rem = blockIdx.y & 3;
  const int qi = (grp == 0) ? 15 - rem : (grp == 1) ? rem : (grp == 2) ? 11 - rem : 4 + rem;
  const int q0 = qi * 128;
  const int wq0 = q0 + wid * 32;

  // Q A-frags: 2 m-tiles x 2 k-chunks (row = r16, k = kk*32 + g*8 + e)
  bf16x8 qf[2][2];
#pragma unroll
  for (int m = 0; m < 2; ++m) {
    const short* qbase = qbf + ((size_t)bh*Tt + wq0 + m*16 + r16)*DHd;
    qf[m][0] = *reinterpret_cast<const bf16x8*>(qbase + g*8);
    qf[m][1] = *reinterpret_cast<const bf16x8*>(qbase + 32 + g*8);
  }

  f32x4 o[2][4];
  float mrow[2][4], lrow[2][4];
#pragma unroll
  for (int m = 0; m < 2; ++m)
#pragma unroll
    for (int i = 0; i < 4; ++i) { o[m][i] = (f32x4)0.0f; mrow[m][i] = -INFINITY; lrow[m][i] = 0.0f; }

  short* Pw = &Ps[wid * 32 * KPAD];
  const int nkv = 2*qi + 2;

  for (int kv = 0; kv < nkv; ++kv) {
    const int kv0 = kv * 64;
    // stage K (row-major) and Vt (transposed: row d, cols k) tiles
#pragma unroll
    for (int c = 0; c < 2; ++c) {
      const int idx = tid + c*256;          // 0..511
      const int row = idx >> 3, cc = idx & 7;
      *reinterpret_cast<bf16x8*>(&Ks[row*KPAD + cc*8]) =
          *reinterpret_cast<const bf16x8*>(kbf + ((size_t)bh*Tt + kv0 + row)*DHd + cc*8);
      *reinterpret_cast<bf16x8*>(&Vts[row*KPAD + cc*8]) =
          *reinterpret_cast<const bf16x8*>(vtb + ((size_t)bh*DHd + row)*Tt + kv0 + cc*8);
    }
    __syncthreads();

    // S = (Q/8) K^T : per wave [32 q x 64 k], 2 m x 4 kt tiles
    f32x4 s[2][4];
    __builtin_amdgcn_s_setprio(1);
#pragma unroll
    for (int kt = 0; kt < 4; ++kt) {
      const bf16x8 k0 = *reinterpret_cast<const bf16x8*>(&Ks[(kt*16 + r16)*KPAD + g*8]);
      const bf16x8 k1 = *reinterpret_cast<const bf16x8*>(&Ks[(kt*16 + r16)*KPAD + 32 + g*8]);
#pragma unroll
      for (int m = 0; m < 2; ++m) {
        f32x4 t = (f32x4)0.0f;
        t = __builtin_amdgcn_mfma_f32_16x16x32_bf16(qf[m][0], k0, t, 0, 0, 0);
        t = __builtin_amdgcn_mfma_f32_16x16x32_bf16(qf[m][1], k1, t, 0, 0, 0);
        s[m][kt] = t;
      }
    }
    __builtin_amdgcn_s_setprio(0);

    // mask + online softmax (row reduce across 16 lanes of each g-group)
#pragma unroll
    for (int m = 0; m < 2; ++m) {
      const int qrd = wq0 + m*16 + g*4;     // D-layout row base
#pragma unroll
      for (int kt = 0; kt < 4; ++kt) {
        const int kg = kv0 + kt*16 + r16;
        const bool mk = (am[b*Tt + kg] != 0);
#pragma unroll
        for (int r = 0; r < 4; ++r)
          if (!mk || kg > qrd + r) s[m][kt][r] = -1e30f;
      }
#pragma unroll
      for (int r = 0; r < 4; ++r) {
        float mx = fmaxf(fmaxf(s[m][0][r], s[m][1][r]), fmaxf(s[m][2][r], s[m][3][r]));
        mx = fmaxf(mx, __shfl_xor(mx, 1));
        mx = fmaxf(mx, __shfl_xor(mx, 2));
        mx = fmaxf(mx, __shfl_xor(mx, 4));
        mx = fmaxf(mx, __shfl_xor(mx, 8));
        const float mnew = fmaxf(mrow[m][r], mx);
        const float alpha = __expf(mrow[m][r] - mnew);
        mrow[m][r] = mnew;
        float rs = 0.f;
#pragma unroll
        for (int kt = 0; kt < 4; ++kt) {
          const float e = __expf(s[m][kt][r] - mnew);
          rs += e;
          Pw[(m*16 + g*4 + r)*KPAD + kt*16 + r16] = f2bf(e);
        }
        rs += __shfl_xor(rs, 1); rs += __shfl_xor(rs, 2);
        rs += __shfl_xor(rs, 4); rs += __shfl_xor(rs, 8);
        lrow[m][r] = lrow[m][r]*alpha + rs;
#pragma unroll
        for (int dt = 0; dt < 4; ++dt) o[m][dt][r] *= alpha;
      }
    }

    // O += P V : A-frag from P (rows q, cols k), B-frag from Vt (rows d, cols k)
    __builtin_amdgcn_s_setprio(1);
#pragma unroll
    for (int ks = 0; ks < 2; ++ks) {
      const bf16x8 pf0 = *reinterpret_cast<const bf16x8*>(&Pw[(r16)*KPAD + ks*32 + g*8]);
      const bf16x8 pf1 = *reinterpret_cast<const bf16x8*>(&Pw[(16 + r16)*KPAD + ks*32 + g*8]);
#pragma unroll
      for (int dt = 0; dt < 4; ++dt) {
        const bf16x8 vf = *reinterpret_cast<const bf16x8*>(&Vts[(dt*16 + r16)*KPAD + ks*32 + g*8]);
        o[0][dt] = __builtin_amdgcn_mfma_f32_16x16x32_bf16(pf0, vf, o[0][dt], 0, 0, 0);
        o[1][dt] = __builtin_amdgcn_mfma_f32_16x16x32_bf16(pf1, vf, o[1][dt], 0, 0, 0);
      }
    }
    __builtin_amdgcn_s_setprio(0);
    __syncthreads();
  }

  // normalize + store to [B,T,C] bf16 (input of out-proj)
#pragma unroll
  for (int m = 0; m < 2; ++m)
#pragma unroll
    for (int r = 0; r < 4; ++r) {
      const float inv = lrow[m][r] > 0.f ? 1.0f / lrow[m][r] : 0.f;
      const int trow = wq0 + m*16 + g*4 + r;
      const size_t base = ((size_t)(b*Tt + trow))*Cc + h*DHd;
#pragma unroll
      for (int dt = 0; dt < 4; ++dt)
        ob[base + dt*16 + r16] = f2bf(o[m][dt][r] * inv);
    }
}

// ---------------- launcher ----------------
extern "C" void kernel_launch(void* const* d_in, const int* in_sizes, int n_in,
                              void* d_out, int out_size, void* d_ws, size_t ws_size,
                              hipStream_t stream) {
  const float* x    = (const float*)d_in[0];
  const int*   am   = (const int*)d_in[1];
  const float* wqkv = (const float*)d_in[2];
  const float* wout = (const float*)d_in[3];
  float* out = (float*)d_out;

  const size_t mc = (size_t)Mm * Cc;        // 8,388,608
  short* ws    = (short*)d_ws;
  short* xb    = ws;                        // [8192,1024] bf16
  short* wqkvb = xb + mc;                   // [3072,1024]
  short* woutb = wqkvb + (size_t)3*Cc*Cc;   // [1024,1024]
  short* qbuf  = woutb + (size_t)Cc*Cc;     // [B,H,T,64]
  short* kbuf  = qbuf + mc;                 // [B,H,T,64]
  short* vtbuf = kbuf + mc;                 // [B,H,64,T] (transposed V)
  short* attnb = xb;                        // reuse x buffer after QKV GEMM

  cvt_bf16<<<(int)((mc/4 + 255)/256), 256, 0, stream>>>(x, xb, (int)(mc/4));
  cvt_bf16<<<(3*Cc*Cc/4 + 255)/256, 256, 0, stream>>>(wqkv, wqkvb, 3*Cc*Cc/4);
  cvt_bf16<<<(Cc*Cc/4 + 255)/256, 256, 0, stream>>>(wout, woutb, Cc*Cc/4);

  gemm_bt<0><<<dim3(3*Cc/128, Mm/128), 256, 0, stream>>>(
      xb, wqkvb, Cc, 3*Cc, nullptr, qbuf, kbuf, vtbuf);

  attn_fwd<<<dim3(Bb*Hh, Tt/128), 256, 0, stream>>>(qbuf, kbuf, vtbuf, am, attnb);

  gemm_bt<1><<<dim3(Cc/128, Mm/128), 256, 0, stream>>>(
      attnb, woutb, Cc, Cc, out, nullptr, nullptr, nullptr);
}

// Round 4
// 249.822 us; speedup vs baseline: 1.6458x; 1.2163x over previous
//
#include <hip/hip_runtime.h>
#include <cstdint>
#include <cmath>

// Causal self-attention: x[B,T,C] -> QKV proj -> flash attn -> out proj.
// B=4 T=2048 C=1024 H=16 DH=64. All matmuls in bf16 MFMA, fp32 accumulate.

#define Bb 4
#define Tt 2048
#define Cc 1024
#define Hh 16
#define DHd 64
#define Mm (Bb*Tt)   // 8192

typedef __attribute__((ext_vector_type(8))) short bf16x8;
typedef __attribute__((ext_vector_type(4))) short s16x4;
typedef __attribute__((ext_vector_type(4))) float f32x4;
typedef __attribute__((ext_vector_type(2))) unsigned int u32x2;

__device__ __forceinline__ short f2bf(float f) {
  uint32_t u = __builtin_bit_cast(uint32_t, f);
  u = (u + 0x7fffu + ((u >> 16) & 1u)) >> 16;   // RNE
  return (short)(uint16_t)u;
}

__device__ __forceinline__ uint32_t cvtpk(float lo, float hi) {
  uint32_t r;
  asm("v_cvt_pk_bf16_f32 %0, %1, %2" : "=v"(r) : "v"(lo), "v"(hi));
  return r;
}

// ---------------- fp32 -> bf16 convert (x4 vectorized) ----------------
__global__ void cvt_bf16(const float* __restrict__ in, short* __restrict__ out, int n4) {
  int i = blockIdx.x * blockDim.x + threadIdx.x;
  if (i >= n4) return;
  f32x4 v = reinterpret_cast<const f32x4*>(in)[i];
  s16x4 o;
  o.x = f2bf(v.x); o.y = f2bf(v.y); o.z = f2bf(v.z); o.w = f2bf(v.w);
  reinterpret_cast<s16x4*>(out)[i] = o;
}

// ---------------- 128x128 bf16 GEMM, C = A * Bt^T (both K-contiguous) ----------------
// MODE 0: QKV epilogue -> scatter to q [B,H,T,64] (scaled log2e/8), k [B,H,T,64],
//         and V TRANSPOSED vt [B,H,64,T]
// MODE 1: plain fp32 store to Cout [M,N]
#define BK 32

template<int MODE>
__global__ __launch_bounds__(256) void gemm_bt(
    const short* __restrict__ A, const short* __restrict__ Bt, int K, int N,
    float* __restrict__ Cout,
    short* __restrict__ qb, short* __restrict__ kb, short* __restrict__ vtb)
{
  __shared__ __align__(16) short As[128*BK];
  __shared__ __align__(16) short Bs[128*BK];
  const int tid = threadIdx.x;
  const int lane = tid & 63, wid = tid >> 6;
  const int wr = wid >> 1, wc = wid & 1;
  const int bm = blockIdx.y, bn = blockIdx.x;
  const int r16 = lane & 15, g = lane >> 4;

  f32x4 acc[4][4];
#pragma unroll
  for (int i = 0; i < 4; ++i)
#pragma unroll
    for (int j = 0; j < 4; ++j) acc[i][j] = (f32x4)0.0f;

  const int srow = lane >> 2;
  const int scol = (lane & 3) * 8;
  const int ch0 = wid * 2;

  const int nk = K / BK;
  for (int kt = 0; kt < nk; ++kt) {
    const int k0 = kt * BK;
#pragma unroll
    for (int c = 0; c < 2; ++c) {
      const int chunk = ch0 + c;
      const int row = chunk * 16 + srow;
      const short* ga = A  + (size_t)(bm*128 + row)*K + k0 + scol;
      const short* gb = Bt + (size_t)(bn*128 + row)*K + k0 + scol;
      __builtin_amdgcn_global_load_lds((const __attribute__((address_space(1))) void*)ga,
                                       (__attribute__((address_space(3))) void*)(&As[chunk*512]), 16, 0, 0);
      __builtin_amdgcn_global_load_lds((const __attribute__((address_space(1))) void*)gb,
                                       (__attribute__((address_space(3))) void*)(&Bs[chunk*512]), 16, 0, 0);
    }
    __syncthreads();

    bf16x8 af[4], bfv[4];
#pragma unroll
    for (int mi = 0; mi < 4; ++mi)
      af[mi] = *reinterpret_cast<const bf16x8*>(&As[(wr*64 + mi*16 + r16)*BK + g*8]);
#pragma unroll
    for (int ni = 0; ni < 4; ++ni)
      bfv[ni] = *reinterpret_cast<const bf16x8*>(&Bs[(wc*64 + ni*16 + r16)*BK + g*8]);
#pragma unroll
    for (int mi = 0; mi < 4; ++mi)
#pragma unroll
      for (int ni = 0; ni < 4; ++ni)
        acc[mi][ni] = __builtin_amdgcn_mfma_f32_16x16x32_bf16(af[mi], bfv[ni], acc[mi][ni], 0, 0, 0);
    __syncthreads();
  }

#pragma unroll
  for (int mi = 0; mi < 4; ++mi) {
    const int row0 = bm*128 + wr*64 + mi*16 + g*4;
#pragma unroll
    for (int ni = 0; ni < 4; ++ni) {
      const int col_g = bn*128 + wc*64 + ni*16 + r16;
#pragma unroll
      for (int r = 0; r < 4; ++r) {
        const float v = acc[mi][ni][r];
        const int rg = row0 + r;
        if (MODE == 1) {
          Cout[(size_t)rg * N + col_g] = v;
        } else {
          const int which = col_g >> 10;          // 0=q 1=k 2=v
          const int hd = col_g & 1023;
          const int h = hd >> 6, d = hd & 63;
          const int b = rg >> 11, t = rg & 2047;
          const int bh = b*Hh + h;
          if (which == 0) {
            qb[(((size_t)bh*Tt + t) << 6) + d] = f2bf(v * 0.18033688f);  // log2e/8
          } else if (which == 1) {
            kb[(((size_t)bh*Tt + t) << 6) + d] = f2bf(v);
          } else {
            vtb[((size_t)bh*DHd + d)*Tt + t] = f2bf(v);   // transposed
          }
        }
      }
    }
  }
}

// ---------------- flash attention, causal + key mask ----------------
// grid: (B*H=64, T/128=16). 4 waves; each wave owns 32 q rows.
// Swapped QK^T (S^T = K·Q^T) -> in-register softmax; PV as O^T = Vt·P^T.
// K/V double-buffered, XOR-swizzled stride-64 LDS; 2 barriers/tile.
// Key mask via per-tile __ballot on am (no precomputed buffer).
__global__ __launch_bounds__(256) void attn_fwd(
    const short* __restrict__ qbf, const short* __restrict__ kbf,
    const short* __restrict__ vtb, const int* __restrict__ am,
    short* __restrict__ ob)
{
  __shared__ __align__(16) short Ks[2][64*64];
  __shared__ __align__(16) short Vts[2][64*64];
  __shared__ __align__(16) short Ps[128*80];     // per-wave 32 rows, stride 80 shorts
  const int tid = threadIdx.x;
  const int lane = tid & 63, wid = tid >> 6;
  const int r16 = lane & 15, g = lane >> 4;
  const int bh = blockIdx.x;
  const int b = bh >> 4, h = bh & 15;
  // balanced qi permutation: heavy blocks first, each CU-set sums equal work
  const int grp = blockIdx.y >> 2, rem = blockIdx.y & 3;
  const int qi = (grp == 0) ? 15 - rem : (grp == 1) ? rem : (grp == 2) ? 11 - rem : 4 + rem;
  const int q0 = qi * 128;
  const int wq0 = q0 + wid * 32;

  // Q fragments (used as B-operand of swapped QK^T): q-col = r16, k = g*8+e
  bf16x8 qf[2][2];
#pragma unroll
  for (int m = 0; m < 2; ++m) {
    const short* qbase = qbf + ((size_t)bh*Tt + wq0 + m*16 + r16)*DHd;
    qf[m][0] = *reinterpret_cast<const bf16x8*>(qbase + g*8);
    qf[m][1] = *reinterpret_cast<const bf16x8*>(qbase + 32 + g*8);
  }

  f32x4 o[2][4];
  float mrow[2], lrow[2];
#pragma unroll
  for (int m = 0; m < 2; ++m) {
    mrow[m] = -INFINITY; lrow[m] = 0.f;
#pragma unroll
    for (int i = 0; i < 4; ++i) o[m][i] = (f32x4)0.0f;
  }

  char* Pw = (char*)Ps + (wid*32 + r16)*160;   // + m*2560 per m-half
  const int nkv = 2*qi + 2;

  const int srow = tid >> 3, scc = tid & 7;    // staging: 2 chunks per thread
  bf16x8 kr[2], vr[2];
  // prologue: stage tile 0
#pragma unroll
  for (int c = 0; c < 2; ++c) {
    const int row = srow + c*32;
    kr[c] = *reinterpret_cast<const bf16x8*>(kbf + ((size_t)bh*Tt + row)*DHd + scc*8);
    vr[c] = *reinterpret_cast<const bf16x8*>(vtb + ((size_t)bh*DHd + row)*Tt + scc*8);
  }
#pragma unroll
  for (int c = 0; c < 2; ++c) {
    const int row = srow + c*32;
    const int off = (row*128 + scc*16) ^ ((row & 7) << 4);
    *reinterpret_cast<bf16x8*>((char*)Ks[0] + off) = kr[c];
    *reinterpret_cast<bf16x8*>((char*)Vts[0] + off) = vr[c];
  }
  __syncthreads();

  for (int kv = 0; kv < nkv; ++kv) {
    const int cur = kv & 1;
    const int kv0 = kv * 64;
    // key-mask word for this tile (coalesced load + ballot; SGPR-resident)
    const unsigned long long mb = __ballot(am[b*Tt + kv0 + lane] != 0);
    if (kv + 1 < nkv) {       // issue next-tile loads early (hide under compute)
#pragma unroll
      for (int c = 0; c < 2; ++c) {
        const int row = srow + c*32;
        kr[c] = *reinterpret_cast<const bf16x8*>(kbf + ((size_t)bh*Tt + kv0 + 64 + row)*DHd + scc*8);
        vr[c] = *reinterpret_cast<const bf16x8*>(vtb + ((size_t)bh*DHd + row)*Tt + kv0 + 64 + scc*8);
      }
    }

    if (kv0 <= wq0 + 31) {    // skip fully-above-diagonal tiles (wave-uniform)
      const char* kbp = (const char*)Ks[cur];
      const char* vbp = (const char*)Vts[cur];
      const int swz = (r16 & 7) << 4;

      // ---- S^T = K · Q^T ----
      f32x4 st[2][4];
      __builtin_amdgcn_s_setprio(1);
#pragma unroll
      for (int kt = 0; kt < 4; ++kt) {
        const int rb = (kt*16 + r16)*128;
        const bf16x8 ka0 = *reinterpret_cast<const bf16x8*>(kbp + ((rb + g*16) ^ swz));
        const bf16x8 ka1 = *reinterpret_cast<const bf16x8*>(kbp + ((rb + 64 + g*16) ^ swz));
#pragma unroll
        for (int m = 0; m < 2; ++m) {
          f32x4 t = (f32x4)0.0f;
          t = __builtin_amdgcn_mfma_f32_16x16x32_bf16(ka0, qf[m][0], t, 0, 0, 0);
          t = __builtin_amdgcn_mfma_f32_16x16x32_bf16(ka1, qf[m][1], t, 0, 0, 0);
          st[m][kt] = t;
        }
      }
      __builtin_amdgcn_s_setprio(0);

      // ---- masking (wave-uniform branches; usually skipped) ----
      const bool notall = (mb != ~0ull);
      const bool diag = (kv0 + 63 > wq0);
      if (diag || notall) {
#pragma unroll
        for (int m = 0; m < 2; ++m) {
          const int qrow = wq0 + m*16 + r16;
#pragma unroll
          for (int kt = 0; kt < 4; ++kt)
#pragma unroll
            for (int r = 0; r < 4; ++r) {
              const int kl = kt*16 + g*4 + r;
              bool ok = !diag || (kv0 + kl <= qrow);
              if (notall) ok = ok && ((mb >> kl) & 1ull);
              if (!ok) st[m][kt][r] = -3.0e38f;
            }
        }
      }

      // ---- in-register online softmax (lane owns one q-row per m) ----
      float mx[2], mnew[2], rs[2];
#pragma unroll
      for (int m = 0; m < 2; ++m) {
        f32x4 t0, t1;
#pragma unroll
        for (int i = 0; i < 4; ++i) { t0[i] = fmaxf(st[m][0][i], st[m][1][i]); t1[i] = fmaxf(st[m][2][i], st[m][3][i]); }
#pragma unroll
        for (int i = 0; i < 4; ++i) t0[i] = fmaxf(t0[i], t1[i]);
        mx[m] = fmaxf(fmaxf(t0[0], t0[1]), fmaxf(t0[2], t0[3]));
      }
      { // interleaved cross-group reduce (2 ds ops deep, 2 chains)
        float a0 = __shfl_xor(mx[0], 16), a1 = __shfl_xor(mx[1], 16);
        mx[0] = fmaxf(mx[0], a0); mx[1] = fmaxf(mx[1], a1);
        a0 = __shfl_xor(mx[0], 32); a1 = __shfl_xor(mx[1], 32);
        mx[0] = fmaxf(mx[0], a0); mx[1] = fmaxf(mx[1], a1);
      }
      const bool grow = __any((mx[0] > mrow[0]) || (mx[1] > mrow[1]));
      mnew[0] = fmaxf(mrow[0], mx[0]);
      mnew[1] = fmaxf(mrow[1], mx[1]);

#pragma unroll
      for (int m = 0; m < 2; ++m) {
#pragma unroll
        for (int kt = 0; kt < 4; ++kt)
#pragma unroll
          for (int r = 0; r < 4; ++r)
            st[m][kt][r] = __builtin_amdgcn_exp2f(st[m][kt][r] - mnew[m]);
        // P -> per-wave LDS (packed b64 writes, conflict-free)
        char* pw = Pw + m*2560;
#pragma unroll
        for (int kt = 0; kt < 4; ++kt) {
          u32x2 w;
          w.x = cvtpk(st[m][kt][0], st[m][kt][1]);
          w.y = cvtpk(st[m][kt][2], st[m][kt][3]);
          *reinterpret_cast<u32x2*>(pw + kt*32 + g*8) = w;
        }
        f32x4 s4;
#pragma unroll
        for (int i = 0; i < 4; ++i) s4[i] = st[m][0][i] + st[m][1][i] + st[m][2][i] + st[m][3][i];
        rs[m] = (s4[0] + s4[1]) + (s4[2] + s4[3]);
      }
      { // interleaved sum reduce
        float a0 = __shfl_xor(rs[0], 16), a1 = __shfl_xor(rs[1], 16);
        rs[0] += a0; rs[1] += a1;
        a0 = __shfl_xor(rs[0], 32); a1 = __shfl_xor(rs[1], 32);
        rs[0] += a0; rs[1] += a1;
      }
      if (grow) {
#pragma unroll
        for (int m = 0; m < 2; ++m) {
          const float alpha = __builtin_amdgcn_exp2f(mrow[m] - mnew[m]);
          mrow[m] = mnew[m];
          lrow[m] = lrow[m]*alpha + rs[m];
#pragma unroll
          for (int dt = 0; dt < 4; ++dt) o[m][dt] *= alpha;
        }
      } else {
        lrow[0] += rs[0]; lrow[1] += rs[1];
      }

      // ensure P-writes complete/ordered before re-fragmented reads
      __builtin_amdgcn_sched_barrier(0);

      // ---- O^T += Vt · P^T ----
      __builtin_amdgcn_s_setprio(1);
#pragma unroll
      for (int ks = 0; ks < 2; ++ks) {
        const bf16x8 pb0 = *reinterpret_cast<const bf16x8*>(Pw + ks*64 + g*16);
        const bf16x8 pb1 = *reinterpret_cast<const bf16x8*>(Pw + 2560 + ks*64 + g*16);
#pragma unroll
        for (int dt = 0; dt < 4; ++dt) {
          const int rb = (dt*16 + r16)*128;
          const bf16x8 va = *reinterpret_cast<const bf16x8*>(vbp + ((rb + ks*64 + g*16) ^ swz));
          o[0][dt] = __builtin_amdgcn_mfma_f32_16x16x32_bf16(va, pb0, o[0][dt], 0, 0, 0);
          o[1][dt] = __builtin_amdgcn_mfma_f32_16x16x32_bf16(va, pb1, o[1][dt], 0, 0, 0);
        }
      }
      __builtin_amdgcn_s_setprio(0);
    }

    // barrier 1: all waves done COMPUTING on buf[cur] before anyone writes buf[cur^1]
    __syncthreads();
    if (kv + 1 < nkv) {
#pragma unroll
      for (int c = 0; c < 2; ++c) {
        const int row = srow + c*32;
        const int off = (row*128 + scc*16) ^ ((row & 7) << 4);
        *reinterpret_cast<bf16x8*>((char*)Ks[cur^1] + off) = kr[c];
        *reinterpret_cast<bf16x8*>((char*)Vts[cur^1] + off) = vr[c];
      }
    }
    // barrier 2: next tile's LDS writes visible to all waves
    __syncthreads();
  }

  // ---- normalize + store O (lane holds q=r16, d=dt*16+g*4+r contiguous) ----
#pragma unroll
  for (int m = 0; m < 2; ++m) {
    const float inv = (mrow[m] > -1e37f) ? 1.0f / lrow[m] : 0.f;
    short* obase = ob + ((size_t)(b*Tt + wq0 + m*16 + r16))*Cc + h*DHd;
#pragma unroll
    for (int dt = 0; dt < 4; ++dt) {
      u32x2 w;
      w.x = cvtpk(o[m][dt][0]*inv, o[m][dt][1]*inv);
      w.y = cvtpk(o[m][dt][2]*inv, o[m][dt][3]*inv);
      *reinterpret_cast<u32x2*>(obase + dt*16 + g*4) = w;
    }
  }
}

// ---------------- launcher ----------------
extern "C" void kernel_launch(void* const* d_in, const int* in_sizes, int n_in,
                              void* d_out, int out_size, void* d_ws, size_t ws_size,
                              hipStream_t stream) {
  const float* x    = (const float*)d_in[0];
  const int*   am   = (const int*)d_in[1];
  const float* wqkv = (const float*)d_in[2];
  const float* wout = (const float*)d_in[3];
  float* out = (float*)d_out;

  const size_t mc = (size_t)Mm * Cc;        // 8,388,608
  short* ws    = (short*)d_ws;
  short* xb    = ws;                        // [8192,1024] bf16
  short* wqkvb = xb + mc;                   // [3072,1024]
  short* woutb = wqkvb + (size_t)3*Cc*Cc;   // [1024,1024]
  short* qbuf  = woutb + (size_t)Cc*Cc;     // [B,H,T,64] (pre-scaled by log2e/8)
  short* kbuf  = qbuf + mc;                 // [B,H,T,64]
  short* vtbuf = kbuf + mc;                 // [B,H,64,T] (transposed V)
  short* attnb = xb;                        // reuse x buffer after QKV GEMM

  cvt_bf16<<<(int)((mc/4 + 255)/256), 256, 0, stream>>>(x, xb, (int)(mc/4));
  cvt_bf16<<<(3*Cc*Cc/4 + 255)/256, 256, 0, stream>>>(wqkv, wqkvb, 3*Cc*Cc/4);
  cvt_bf16<<<(Cc*Cc/4 + 255)/256, 256, 0, stream>>>(wout, woutb, Cc*Cc/4);

  gemm_bt<0><<<dim3(3*Cc/128, Mm/128), 256, 0, stream>>>(
      xb, wqkvb, Cc, 3*Cc, nullptr, qbuf, kbuf, vtbuf);

  attn_fwd<<<dim3(Bb*Hh, Tt/128), 256, 0, stream>>>(qbuf, kbuf, vtbuf, am, attnb);

  gemm_bt<1><<<dim3(Cc/128, Mm/128), 256, 0, stream>>>(
      attnb, woutb, Cc, Cc, out, nullptr, nullptr, nullptr);
}

// Round 5
// 238.881 us; speedup vs baseline: 1.7212x; 1.0458x over previous
//
#include <hip/hip_runtime.h>
#include <cstdint>
#include <cmath>

// Causal self-attention: x[B,T,C] -> QKV proj -> flash attn -> out proj.
// B=4 T=2048 C=1024 H=16 DH=64. All matmuls in bf16 MFMA, fp32 accumulate.

#define Bb 4
#define Tt 2048
#define Cc 1024
#define Hh 16
#define DHd 64
#define Mm (Bb*Tt)   // 8192

typedef __attribute__((ext_vector_type(8))) short bf16x8;
typedef __attribute__((ext_vector_type(4))) short s16x4;
typedef __attribute__((ext_vector_type(4))) float f32x4;
typedef __attribute__((ext_vector_type(2))) unsigned int u32x2;

__device__ __forceinline__ short f2bf(float f) {
  uint32_t u = __builtin_bit_cast(uint32_t, f);
  u = (u + 0x7fffu + ((u >> 16) & 1u)) >> 16;   // RNE
  return (short)(uint16_t)u;
}

__device__ __forceinline__ uint32_t cvtpk(float lo, float hi) {
  uint32_t r;
  asm("v_cvt_pk_bf16_f32 %0, %1, %2" : "=v"(r) : "v"(lo), "v"(hi));
  return r;
}

// ---------------- fp32 -> bf16 convert (x4 vectorized) ----------------
__global__ void cvt_bf16(const float* __restrict__ in, short* __restrict__ out, int n4) {
  int i = blockIdx.x * blockDim.x + threadIdx.x;
  if (i >= n4) return;
  f32x4 v = reinterpret_cast<const f32x4*>(in)[i];
  s16x4 o;
  o.x = f2bf(v.x); o.y = f2bf(v.y); o.z = f2bf(v.z); o.w = f2bf(v.w);
  reinterpret_cast<s16x4*>(out)[i] = o;
}

// ================= 256x256 8-phase bf16 GEMM (QKV projection) =================
// C[8192,3072] = A[8192,1024] * Bt[3072,1024]^T, epilogue scatters q/k/vt.
// 8 waves (2M x 4N), BK=64, 2 K-tiles per iteration, 8 phases.
// LDS swizzle: physical slot = logical slot ^ (row&7) (16B slots, 8 per 128B row);
// staged via pre-swizzled GLOBAL source (linear LDS dest), read with same XOR.
__global__ __launch_bounds__(512, 2) void gemm256_qkv(
    const short* __restrict__ A, const short* __restrict__ Bt,
    short* __restrict__ qb, short* __restrict__ kb, short* __restrict__ vtb)
{
  constexpr int NKT = 16;                    // K=1024 -> 16 K-tiles of 64
  __shared__ __align__(16) short As[2][256*64];
  __shared__ __align__(16) short Bs[2][256*64];
  const int tid = threadIdx.x;
  const int lane = tid & 63;
  const int r16 = lane & 15, g = lane >> 4;
  const int wid = tid >> 6;
  const int wm = wid >> 2, wn = wid & 3;

  // bijective XCD swizzle (384 blocks, 48/XCD)
  const int nbx = gridDim.x;                 // 12
  const int lin = blockIdx.y * nbx + blockIdx.x;
  const int cpx = (nbx * gridDim.y) >> 3;    // 48
  const int swz = (lin & 7) * cpx + (lin >> 3);
  const int bm = swz / nbx, bn = swz % nbx;

  f32x4 acc[8][4];
#pragma unroll
  for (int i = 0; i < 8; ++i)
#pragma unroll
    for (int j = 0; j < 4; ++j) acc[i][j] = (f32x4)0.0f;

  // stage half-tile: HF 0=A.h0 1=A.h1 2=B.h0 3=B.h1 into slot SLOT, K-tile KT
#define STAGE(HF, SLOT, KT) do {                                               \
    const int kt_ = (KT);                                                      \
    if (kt_ < NKT) {                                                           \
      const short* gsrc_ = ((HF) & 2) ? Bt : A;                                \
      const int rbase_ = (((HF) & 2) ? bn : bm) * 256 + ((HF) & 1) * 128;      \
      short* lbase_ = (((HF) & 2) ? Bs[SLOT] : As[SLOT]) + ((HF) & 1) * 8192;  \
      _Pragma("unroll")                                                        \
      for (int j_ = 0; j_ < 2; ++j_) {                                         \
        const int tt_ = j_*512 + tid;                                          \
        const int row_ = tt_ >> 3, p_ = tt_ & 7;                               \
        const short* src_ = gsrc_ + (size_t)(rbase_ + row_) * 1024             \
                            + kt_*64 + ((p_ ^ (row_ & 7)) * 8);                \
        __builtin_amdgcn_global_load_lds(                                      \
            (const __attribute__((address_space(1))) void*)src_,               \
            (__attribute__((address_space(3))) void*)(lbase_ + (j_*512 + (tid & 448))*8), \
            16, 0, 0);                                                         \
      }                                                                        \
    }                                                                          \
  } while (0)

  bf16x8 a[4][2], b[2][2][2];

#define LDA(SLOT, MH) do {                                                     \
    _Pragma("unroll")                                                          \
    for (int mi_ = 0; mi_ < 4; ++mi_) {                                        \
      const int row_ = wm*128 + ((MH)*4 + mi_)*16 + r16;                       \
      _Pragma("unroll")                                                        \
      for (int ks_ = 0; ks_ < 2; ++ks_)                                        \
        a[mi_][ks_] = *reinterpret_cast<const bf16x8*>(                        \
            (const char*)As[SLOT] + row_*128 + (((ks_*4 + g) ^ (row_ & 7)) << 4)); \
    }                                                                          \
  } while (0)

#define LDB(NH, SLOT) do {                                                     \
    _Pragma("unroll")                                                          \
    for (int ni_ = 0; ni_ < 2; ++ni_) {                                        \
      const int row_ = wn*64 + ((NH)*2 + ni_)*16 + r16;                        \
      _Pragma("unroll")                                                        \
      for (int ks_ = 0; ks_ < 2; ++ks_)                                        \
        b[NH][ni_][ks_] = *reinterpret_cast<const bf16x8*>(                    \
            (const char*)Bs[SLOT] + row_*128 + (((ks_*4 + g) ^ (row_ & 7)) << 4)); \
    }                                                                          \
  } while (0)

#define QUAD(MH, NH) do {                                                      \
    __builtin_amdgcn_s_setprio(1);                                             \
    _Pragma("unroll")                                                          \
    for (int ks_ = 0; ks_ < 2; ++ks_)                                          \
      _Pragma("unroll")                                                        \
      for (int mi_ = 0; mi_ < 4; ++mi_)                                        \
        _Pragma("unroll")                                                      \
        for (int ni_ = 0; ni_ < 2; ++ni_)                                      \
          acc[(MH)*4+mi_][(NH)*2+ni_] = __builtin_amdgcn_mfma_f32_16x16x32_bf16( \
              a[mi_][ks_], b[NH][ni_][ks_], acc[(MH)*4+mi_][(NH)*2+ni_], 0,0,0); \
    __builtin_amdgcn_s_setprio(0);                                             \
  } while (0)

#define BARRIER __builtin_amdgcn_s_barrier()
#define LGKM0 asm volatile("s_waitcnt lgkmcnt(0)")

  // prologue: K0 fully + K1.h0 (streams 0..4 = 10 loads); wait K0 (leave 2)
  STAGE(0, 0, 0); STAGE(1, 0, 0); STAGE(2, 0, 0); STAGE(3, 0, 0);
  STAGE(0, 1, 1);
  asm volatile("s_waitcnt vmcnt(2)");
  BARRIER;

#pragma unroll 1
  for (int i = 0; i < NKT/2; ++i) {
    const int t1 = 2*i + 1, t2 = 2*i + 2, t3 = 2*i + 3;
    // P1: reads slot0 (A mh0 + B nh0); stage K(2i+1).h1 -> slot1
    LDA(0, 0); LDB(0, 0);
    STAGE(1, 1, t1);
    BARRIER; LGKM0; QUAD(0, 0); BARRIER;
    // P2: B nh1 from slot0; stage K(2i+1).B.h0
    LDB(1, 0);
    STAGE(2, 1, t1);
    BARRIER; LGKM0; QUAD(0, 1); BARRIER;
    // P3: A mh1 from slot0; stage K(2i+1).B.h1
    LDA(0, 1);
    STAGE(3, 1, t1);
    BARRIER; LGKM0; QUAD(1, 0); BARRIER;
    // P4: stage K(2i+2).A.h0 -> slot0; counted vmcnt: K(2i+1) landed
    STAGE(0, 0, t2);
    if (i == NKT/2 - 1) { asm volatile("s_waitcnt vmcnt(0)"); }
    else                { asm volatile("s_waitcnt vmcnt(2)"); }
    BARRIER; LGKM0; QUAD(1, 1); BARRIER;
    // P5: reads slot1; stage K(2i+2).A.h1
    LDA(1, 0); LDB(0, 1);
    STAGE(1, 0, t2);
    BARRIER; LGKM0; QUAD(0, 0); BARRIER;
    // P6
    LDB(1, 1);
    STAGE(2, 0, t2);
    BARRIER; LGKM0; QUAD(0, 1); BARRIER;
    // P7
    LDA(1, 1);
    STAGE(3, 0, t2);
    BARRIER; LGKM0; QUAD(1, 0); BARRIER;
    // P8: stage K(2i+3).A.h0 -> slot1; counted vmcnt: K(2i+2) landed
    STAGE(0, 1, t3);
    asm volatile("s_waitcnt vmcnt(2)");
    BARRIER; LGKM0; QUAD(1, 1); BARRIER;
  }

  // epilogue: scatter QKV.  D layout: row = g*4+r (M), col = r16 (N)
#pragma unroll
  for (int fm = 0; fm < 8; ++fm) {
    const int row0 = bm*256 + wm*128 + fm*16 + g*4;
#pragma unroll
    for (int fn = 0; fn < 4; ++fn) {
      const int col_g = bn*256 + wn*64 + fn*16 + r16;
      const int which = col_g >> 10;          // 0=q 1=k 2=v
      const int hd = col_g & 1023;
      const int h = hd >> 6, d = hd & 63;
#pragma unroll
      for (int r = 0; r < 4; ++r) {
        const float v = acc[fm][fn][r];
        const int rg = row0 + r;
        const int bidx = rg >> 11, t = rg & 2047;
        const int bh = bidx*Hh + h;
        if (which == 0) {
          qb[(((size_t)bh*Tt + t) << 6) + d] = f2bf(v * 0.18033688f);  // log2e/8
        } else if (which == 1) {
          kb[(((size_t)bh*Tt + t) << 6) + d] = f2bf(v);
        } else {
          vtb[((size_t)bh*DHd + d)*Tt + t] = f2bf(v);   // transposed
        }
      }
    }
  }
#undef STAGE
#undef LDA
#undef LDB
#undef QUAD
#undef BARRIER
#undef LGKM0
}

// ---------------- 128x128 bf16 GEMM (out projection), C = A * Bt^T ----------------
#define BK 32

template<int MODE>
__global__ __launch_bounds__(256) void gemm_bt(
    const short* __restrict__ A, const short* __restrict__ Bt, int K, int N,
    float* __restrict__ Cout)
{
  __shared__ __align__(16) short As[128*BK];
  __shared__ __align__(16) short Bs[128*BK];
  const int tid = threadIdx.x;
  const int lane = tid & 63, wid = tid >> 6;
  const int wr = wid >> 1, wc = wid & 1;
  const int bm = blockIdx.y, bn = blockIdx.x;
  const int r16 = lane & 15, g = lane >> 4;

  f32x4 acc[4][4];
#pragma unroll
  for (int i = 0; i < 4; ++i)
#pragma unroll
    for (int j = 0; j < 4; ++j) acc[i][j] = (f32x4)0.0f;

  const int srow = lane >> 2;
  const int scol = (lane & 3) * 8;
  const int ch0 = wid * 2;

  const int nk = K / BK;
  for (int kt = 0; kt < nk; ++kt) {
    const int k0 = kt * BK;
#pragma unroll
    for (int c = 0; c < 2; ++c) {
      const int chunk = ch0 + c;
      const int row = chunk * 16 + srow;
      const short* ga = A  + (size_t)(bm*128 + row)*K + k0 + scol;
      const short* gb = Bt + (size_t)(bn*128 + row)*K + k0 + scol;
      __builtin_amdgcn_global_load_lds((const __attribute__((address_space(1))) void*)ga,
                                       (__attribute__((address_space(3))) void*)(&As[chunk*512]), 16, 0, 0);
      __builtin_amdgcn_global_load_lds((const __attribute__((address_space(1))) void*)gb,
                                       (__attribute__((address_space(3))) void*)(&Bs[chunk*512]), 16, 0, 0);
    }
    __syncthreads();

    bf16x8 af[4], bfv[4];
#pragma unroll
    for (int mi = 0; mi < 4; ++mi)
      af[mi] = *reinterpret_cast<const bf16x8*>(&As[(wr*64 + mi*16 + r16)*BK + g*8]);
#pragma unroll
    for (int ni = 0; ni < 4; ++ni)
      bfv[ni] = *reinterpret_cast<const bf16x8*>(&Bs[(wc*64 + ni*16 + r16)*BK + g*8]);
#pragma unroll
    for (int mi = 0; mi < 4; ++mi)
#pragma unroll
      for (int ni = 0; ni < 4; ++ni)
        acc[mi][ni] = __builtin_amdgcn_mfma_f32_16x16x32_bf16(af[mi], bfv[ni], acc[mi][ni], 0, 0, 0);
    __syncthreads();
  }

#pragma unroll
  for (int mi = 0; mi < 4; ++mi) {
    const int row0 = bm*128 + wr*64 + mi*16 + g*4;
#pragma unroll
    for (int ni = 0; ni < 4; ++ni) {
      const int col_g = bn*128 + wc*64 + ni*16 + r16;
#pragma unroll
      for (int r = 0; r < 4; ++r)
        Cout[(size_t)(row0 + r) * N + col_g] = acc[mi][ni][r];
    }
  }
}

// ---------------- flash attention, causal + key mask ----------------
// grid: (B*H=64, T/128=16). 4 waves; each wave owns 32 q rows.
// Swapped QK^T (S^T = K·Q^T) -> in-register softmax; PV as O^T = Vt·P^T.
// K/V double-buffered, XOR-swizzled stride-64 LDS; 1 barrier/tile.
// Defer-rescale (THR=8 in log2 domain).
__global__ __launch_bounds__(256) void attn_fwd(
    const short* __restrict__ qbf, const short* __restrict__ kbf,
    const short* __restrict__ vtb, const int* __restrict__ am,
    short* __restrict__ ob)
{
  __shared__ __align__(16) short Ks[2][64*64];
  __shared__ __align__(16) short Vts[2][64*64];
  __shared__ __align__(16) short Ps[128*72];     // per-wave 32 rows, stride 144 B
  const int tid = threadIdx.x;
  const int lane = tid & 63, wid = tid >> 6;
  const int r16 = lane & 15, g = lane >> 4;
  const int bh = blockIdx.x;
  const int b = bh >> 4, h = bh & 15;
  const int grp = blockIdx.y >> 2, rem = blockIdx.y & 3;
  const int qi = (grp == 0) ? 15 - rem : (grp == 1) ? rem : (grp == 2) ? 11 - rem : 4 + rem;
  const int q0 = qi * 128;
  const int wq0 = q0 + wid * 32;

  // Q fragments (B-operand of swapped QK^T): q-col = r16, k = g*8+e
  bf16x8 qf[2][2];
#pragma unroll
  for (int m = 0; m < 2; ++m) {
    const short* qbase = qbf + ((size_t)bh*Tt + wq0 + m*16 + r16)*DHd;
    qf[m][0] = *reinterpret_cast<const bf16x8*>(qbase + g*8);
    qf[m][1] = *reinterpret_cast<const bf16x8*>(qbase + 32 + g*8);
  }

  f32x4 o[2][4];
  float mrow[2], lrow[2];
#pragma unroll
  for (int m = 0; m < 2; ++m) {
    mrow[m] = -INFINITY; lrow[m] = 0.f;
#pragma unroll
    for (int i = 0; i < 4; ++i) o[m][i] = (f32x4)0.0f;
  }

  char* Pw = (char*)Ps + (wid*32 + r16)*144;   // + m*2304 per m-half
  const int nkv = 2*qi + 2;

  const int srow = tid >> 3, scc = tid & 7;
  bf16x8 kr[2], vr[2];
#pragma unroll
  for (int c = 0; c < 2; ++c) {
    const int row = srow + c*32;
    kr[c] = *reinterpret_cast<const bf16x8*>(kbf + ((size_t)bh*Tt + row)*DHd + scc*8);
    vr[c] = *reinterpret_cast<const bf16x8*>(vtb + ((size_t)bh*DHd + row)*Tt + scc*8);
  }
#pragma unroll
  for (int c = 0; c < 2; ++c) {
    const int row = srow + c*32;
    const int off = (row*128 + scc*16) ^ ((row & 7) << 4);
    *reinterpret_cast<bf16x8*>((char*)Ks[0] + off) = kr[c];
    *reinterpret_cast<bf16x8*>((char*)Vts[0] + off) = vr[c];
  }
  __syncthreads();

  for (int kv = 0; kv < nkv; ++kv) {
    const int cur = kv & 1;
    const int kv0 = kv * 64;
    const unsigned long long mb = __ballot(am[b*Tt + kv0 + lane] != 0);
    if (kv + 1 < nkv) {       // issue next-tile loads early
#pragma unroll
      for (int c = 0; c < 2; ++c) {
        const int row = srow + c*32;
        kr[c] = *reinterpret_cast<const bf16x8*>(kbf + ((size_t)bh*Tt + kv0 + 64 + row)*DHd + scc*8);
        vr[c] = *reinterpret_cast<const bf16x8*>(vtb + ((size_t)bh*DHd + row)*Tt + kv0 + 64 + scc*8);
      }
    }

    if (kv0 <= wq0 + 31) {    // skip fully-above-diagonal tiles (wave-uniform)
      const char* kbp = (const char*)Ks[cur];
      const char* vbp = (const char*)Vts[cur];
      const int swzr = (r16 & 7) << 4;

      // ---- S^T = K · Q^T ----
      f32x4 st[2][4];
      __builtin_amdgcn_s_setprio(1);
#pragma unroll
      for (int kt = 0; kt < 4; ++kt) {
        const int rb = (kt*16 + r16)*128;
        const bf16x8 ka0 = *reinterpret_cast<const bf16x8*>(kbp + ((rb + g*16) ^ swzr));
        const bf16x8 ka1 = *reinterpret_cast<const bf16x8*>(kbp + ((rb + 64 + g*16) ^ swzr));
#pragma unroll
        for (int m = 0; m < 2; ++m) {
          f32x4 t = (f32x4)0.0f;
          t = __builtin_amdgcn_mfma_f32_16x16x32_bf16(ka0, qf[m][0], t, 0, 0, 0);
          t = __builtin_amdgcn_mfma_f32_16x16x32_bf16(ka1, qf[m][1], t, 0, 0, 0);
          st[m][kt] = t;
        }
      }
      __builtin_amdgcn_s_setprio(0);

      // ---- masking (wave-uniform branch; usually skipped) ----
      const bool notall = (mb != ~0ull);
      const bool diag = (kv0 + 63 > wq0);
      if (diag || notall) {
#pragma unroll
        for (int m = 0; m < 2; ++m) {
          const int qrow = wq0 + m*16 + r16;
#pragma unroll
          for (int kt = 0; kt < 4; ++kt)
#pragma unroll
            for (int r = 0; r < 4; ++r) {
              const int kl = kt*16 + g*4 + r;
              bool ok = !diag || (kv0 + kl <= qrow);
              if (notall) ok = ok && ((mb >> kl) & 1ull);
              if (!ok) st[m][kt][r] = -3.0e38f;
            }
        }
      }

      // ---- in-register online softmax + defer-rescale (THR=8) ----
      float mx[2], rs[2];
#pragma unroll
      for (int m = 0; m < 2; ++m) {
        f32x4 t0, t1;
#pragma unroll
        for (int i = 0; i < 4; ++i) { t0[i] = fmaxf(st[m][0][i], st[m][1][i]); t1[i] = fmaxf(st[m][2][i], st[m][3][i]); }
#pragma unroll
        for (int i = 0; i < 4; ++i) t0[i] = fmaxf(t0[i], t1[i]);
        mx[m] = fmaxf(fmaxf(t0[0], t0[1]), fmaxf(t0[2], t0[3]));
      }
      {
        float a0 = __shfl_xor(mx[0], 16), a1 = __shfl_xor(mx[1], 16);
        mx[0] = fmaxf(mx[0], a0); mx[1] = fmaxf(mx[1], a1);
        a0 = __shfl_xor(mx[0], 32); a1 = __shfl_xor(mx[1], 32);
        mx[0] = fmaxf(mx[0], a0); mx[1] = fmaxf(mx[1], a1);
      }
      const bool need = __any((mx[0] > mrow[0] + 8.f) || (mx[1] > mrow[1] + 8.f));
      if (need) {
#pragma unroll
        for (int m = 0; m < 2; ++m) {
          const float mnew = fmaxf(mrow[m], mx[m]);
          const float alpha = __builtin_amdgcn_exp2f(mrow[m] - mnew);
          mrow[m] = mnew;
          lrow[m] *= alpha;
#pragma unroll
          for (int dt = 0; dt < 4; ++dt) o[m][dt] *= alpha;
        }
      }

#pragma unroll
      for (int m = 0; m < 2; ++m) {
#pragma unroll
        for (int kt = 0; kt < 4; ++kt)
#pragma unroll
          for (int r = 0; r < 4; ++r)
            st[m][kt][r] = __builtin_amdgcn_exp2f(st[m][kt][r] - mrow[m]);
        char* pw = Pw + m*2304;
#pragma unroll
        for (int kt = 0; kt < 4; ++kt) {
          u32x2 w;
          w.x = cvtpk(st[m][kt][0], st[m][kt][1]);
          w.y = cvtpk(st[m][kt][2], st[m][kt][3]);
          *reinterpret_cast<u32x2*>(pw + kt*32 + g*8) = w;
        }
        f32x4 s4;
#pragma unroll
        for (int i = 0; i < 4; ++i) s4[i] = st[m][0][i] + st[m][1][i] + st[m][2][i] + st[m][3][i];
        rs[m] = (s4[0] + s4[1]) + (s4[2] + s4[3]);
      }
      {
        float a0 = __shfl_xor(rs[0], 16), a1 = __shfl_xor(rs[1], 16);
        rs[0] += a0; rs[1] += a1;
        a0 = __shfl_xor(rs[0], 32); a1 = __shfl_xor(rs[1], 32);
        rs[0] += a0; rs[1] += a1;
      }
      lrow[0] += rs[0]; lrow[1] += rs[1];

      __builtin_amdgcn_sched_barrier(0);

      // ---- O^T += Vt · P^T ----
      __builtin_amdgcn_s_setprio(1);
#pragma unroll
      for (int ks = 0; ks < 2; ++ks) {
        const bf16x8 pb0 = *reinterpret_cast<const bf16x8*>(Pw + ks*64 + g*16);
        const bf16x8 pb1 = *reinterpret_cast<const bf16x8*>(Pw + 2304 + ks*64 + g*16);
#pragma unroll
        for (int dt = 0; dt < 4; ++dt) {
          const int rb = (dt*16 + r16)*128;
          const bf16x8 va = *reinterpret_cast<const bf16x8*>(vbp + ((rb + ks*64 + g*16) ^ swzr));
          o[0][dt] = __builtin_amdgcn_mfma_f32_16x16x32_bf16(va, pb0, o[0][dt], 0, 0, 0);
          o[1][dt] = __builtin_amdgcn_mfma_f32_16x16x32_bf16(va, pb1, o[1][dt], 0, 0, 0);
        }
      }
      __builtin_amdgcn_s_setprio(0);
    }

    if (kv + 1 < nkv) {
#pragma unroll
      for (int c = 0; c < 2; ++c) {
        const int row = srow + c*32;
        const int off = (row*128 + scc*16) ^ ((row & 7) << 4);
        *reinterpret_cast<bf16x8*>((char*)Ks[cur^1] + off) = kr[c];
        *reinterpret_cast<bf16x8*>((char*)Vts[cur^1] + off) = vr[c];
      }
    }
    // single barrier: all waves done with buf[cur] reads (this iter) and
    // buf[cur^1] writes (above) before anyone proceeds.
    __syncthreads();
  }

  // ---- normalize + store O (lane holds q=r16, d=dt*16+g*4+r contiguous) ----
#pragma unroll
  for (int m = 0; m < 2; ++m) {
    const float inv = (mrow[m] > -1e37f) ? 1.0f / lrow[m] : 0.f;
    short* obase = ob + ((size_t)(b*Tt + wq0 + m*16 + r16))*Cc + h*DHd;
#pragma unroll
    for (int dt = 0; dt < 4; ++dt) {
      u32x2 w;
      w.x = cvtpk(o[m][dt][0]*inv, o[m][dt][1]*inv);
      w.y = cvtpk(o[m][dt][2]*inv, o[m][dt][3]*inv);
      *reinterpret_cast<u32x2*>(obase + dt*16 + g*4) = w;
    }
  }
}

// ---------------- launcher ----------------
extern "C" void kernel_launch(void* const* d_in, const int* in_sizes, int n_in,
                              void* d_out, int out_size, void* d_ws, size_t ws_size,
                              hipStream_t stream) {
  const float* x    = (const float*)d_in[0];
  const int*   am   = (const int*)d_in[1];
  const float* wqkv = (const float*)d_in[2];
  const float* wout = (const float*)d_in[3];
  float* out = (float*)d_out;

  const size_t mc = (size_t)Mm * Cc;        // 8,388,608
  short* ws    = (short*)d_ws;
  short* xb    = ws;                        // [8192,1024] bf16
  short* wqkvb = xb + mc;                   // [3072,1024]
  short* woutb = wqkvb + (size_t)3*Cc*Cc;   // [1024,1024]
  short* qbuf  = woutb + (size_t)Cc*Cc;     // [B,H,T,64] (pre-scaled by log2e/8)
  short* kbuf  = qbuf + mc;                 // [B,H,T,64]
  short* vtbuf = kbuf + mc;                 // [B,H,64,T] (transposed V)
  short* attnb = xb;                        // reuse x buffer after QKV GEMM

  cvt_bf16<<<(int)((mc/4 + 255)/256), 256, 0, stream>>>(x, xb, (int)(mc/4));
  cvt_bf16<<<(3*Cc*Cc/4 + 255)/256, 256, 0, stream>>>(wqkv, wqkvb, 3*Cc*Cc/4);
  cvt_bf16<<<(Cc*Cc/4 + 255)/256, 256, 0, stream>>>(wout, woutb, Cc*Cc/4);

  gemm256_qkv<<<dim3(3*Cc/256, Mm/256), 512, 0, stream>>>(
      xb, wqkvb, qbuf, kbuf, vtbuf);

  attn_fwd<<<dim3(Bb*Hh, Tt/128), 256, 0, stream>>>(qbuf, kbuf, vtbuf, am, attnb);

  gemm_bt<1><<<dim3(Cc/128, Mm/128), 256, 0, stream>>>(
      attnb, woutb, Cc, Cc, out);
}

// Round 6
// 223.809 us; speedup vs baseline: 1.8371x; 1.0673x over previous
//
#include <hip/hip_runtime.h>
#include <cstdint>
#include <cmath>

// Causal self-attention: x[B,T,C] -> QKV proj -> flash attn -> out proj.
// B=4 T=2048 C=1024 H=16 DH=64. All matmuls in bf16 MFMA, fp32 accumulate.

#define Bb 4
#define Tt 2048
#define Cc 1024
#define Hh 16
#define DHd 64
#define Mm (Bb*Tt)   // 8192

typedef __attribute__((ext_vector_type(8))) short bf16x8;
typedef __attribute__((ext_vector_type(4))) short s16x4;
typedef __attribute__((ext_vector_type(4))) float f32x4;
typedef __attribute__((ext_vector_type(2))) unsigned int u32x2;

__device__ __forceinline__ short f2bf(float f) {
  uint32_t u = __builtin_bit_cast(uint32_t, f);
  u = (u + 0x7fffu + ((u >> 16) & 1u)) >> 16;   // RNE
  return (short)(uint16_t)u;
}

__device__ __forceinline__ uint32_t cvtpk(float lo, float hi) {
  uint32_t r;
  asm("v_cvt_pk_bf16_f32 %0, %1, %2" : "=v"(r) : "v"(lo), "v"(hi));
  return r;
}

// ---------------- fp32 -> bf16 convert (x4 vectorized) ----------------
__global__ void cvt_bf16(const float* __restrict__ in, short* __restrict__ out, int n4) {
  int i = blockIdx.x * blockDim.x + threadIdx.x;
  if (i >= n4) return;
  f32x4 v = reinterpret_cast<const f32x4*>(in)[i];
  s16x4 o;
  o.x = f2bf(v.x); o.y = f2bf(v.y); o.z = f2bf(v.z); o.w = f2bf(v.w);
  reinterpret_cast<s16x4*>(out)[i] = o;
}

// ---------------- 128x128 bf16 GEMM, C = A * Bt^T (both K-contiguous) ----------------
// MODE 0: QKV epilogue -> scatter to q [B,H,T,64] (scaled log2e/8), k [B,H,T,64],
//         and V TRANSPOSED vt [B,H,64,T] (packed b64 stores along t)
// MODE 1: plain fp32 store to Cout [M,N]
#define BK 32

template<int MODE>
__global__ __launch_bounds__(256) void gemm_bt(
    const short* __restrict__ A, const short* __restrict__ Bt, int K, int N,
    float* __restrict__ Cout,
    short* __restrict__ qb, short* __restrict__ kb, short* __restrict__ vtb)
{
  __shared__ __align__(16) short As[128*BK];
  __shared__ __align__(16) short Bs[128*BK];
  const int tid = threadIdx.x;
  const int lane = tid & 63, wid = tid >> 6;
  const int wr = wid >> 1, wc = wid & 1;
  const int bm = blockIdx.y, bn = blockIdx.x;
  const int r16 = lane & 15, g = lane >> 4;

  f32x4 acc[4][4];
#pragma unroll
  for (int i = 0; i < 4; ++i)
#pragma unroll
    for (int j = 0; j < 4; ++j) acc[i][j] = (f32x4)0.0f;

  const int srow = lane >> 2;
  const int scol = (lane & 3) * 8;
  const int ch0 = wid * 2;

  const int nk = K / BK;
  for (int kt = 0; kt < nk; ++kt) {
    const int k0 = kt * BK;
#pragma unroll
    for (int c = 0; c < 2; ++c) {
      const int chunk = ch0 + c;
      const int row = chunk * 16 + srow;
      const short* ga = A  + (size_t)(bm*128 + row)*K + k0 + scol;
      const short* gb = Bt + (size_t)(bn*128 + row)*K + k0 + scol;
      __builtin_amdgcn_global_load_lds((const __attribute__((address_space(1))) void*)ga,
                                       (__attribute__((address_space(3))) void*)(&As[chunk*512]), 16, 0, 0);
      __builtin_amdgcn_global_load_lds((const __attribute__((address_space(1))) void*)gb,
                                       (__attribute__((address_space(3))) void*)(&Bs[chunk*512]), 16, 0, 0);
    }
    __syncthreads();

    bf16x8 af[4], bfv[4];
#pragma unroll
    for (int mi = 0; mi < 4; ++mi)
      af[mi] = *reinterpret_cast<const bf16x8*>(&As[(wr*64 + mi*16 + r16)*BK + g*8]);
#pragma unroll
    for (int ni = 0; ni < 4; ++ni)
      bfv[ni] = *reinterpret_cast<const bf16x8*>(&Bs[(wc*64 + ni*16 + r16)*BK + g*8]);
#pragma unroll
    for (int mi = 0; mi < 4; ++mi)
#pragma unroll
      for (int ni = 0; ni < 4; ++ni)
        acc[mi][ni] = __builtin_amdgcn_mfma_f32_16x16x32_bf16(af[mi], bfv[ni], acc[mi][ni], 0, 0, 0);
    __syncthreads();
  }

  // epilogue: D layout col = lane&15, row = (lane>>4)*4 + r
#pragma unroll
  for (int mi = 0; mi < 4; ++mi) {
    const int row0 = bm*128 + wr*64 + mi*16 + g*4;
#pragma unroll
    for (int ni = 0; ni < 4; ++ni) {
      const int col_g = bn*128 + wc*64 + ni*16 + r16;
      if (MODE == 1) {
#pragma unroll
        for (int r = 0; r < 4; ++r)
          Cout[(size_t)(row0 + r) * N + col_g] = acc[mi][ni][r];
      } else {
        const int which = col_g >> 10;          // 0=q 1=k 2=v
        const int hd = col_g & 1023;
        const int h = hd >> 6, d = hd & 63;
        const int b = row0 >> 11, t0 = row0 & 2047;
        const int bh = b*Hh + h;
        if (which == 0) {
#pragma unroll
          for (int r = 0; r < 4; ++r)
            qb[(((size_t)bh*Tt + t0 + r) << 6) + d] = f2bf(acc[mi][ni][r] * 0.18033688f); // log2e/8
        } else if (which == 1) {
#pragma unroll
          for (int r = 0; r < 4; ++r)
            kb[(((size_t)bh*Tt + t0 + r) << 6) + d] = f2bf(acc[mi][ni][r]);
        } else {
          // transposed V: t contiguous along register index -> one packed b64 store
          u32x2 w;
          w.x = cvtpk(acc[mi][ni][0], acc[mi][ni][1]);
          w.y = cvtpk(acc[mi][ni][2], acc[mi][ni][3]);
          *reinterpret_cast<u32x2*>(vtb + ((size_t)bh*DHd + d)*Tt + t0) = w;
        }
      }
    }
  }
}

// ---------------- flash attention, causal + key mask ----------------
// grid: (B*H=64, T/128=16). 4 waves; each wave owns 32 q rows.
// Swapped QK^T (S^T = K·Q^T) -> in-register softmax; PV as O^T = Vt·P^T.
// K/V double-buffered, XOR-swizzled stride-64 LDS; 1 barrier/tile.
// Defer-rescale (THR=8 in log2 domain).
__global__ __launch_bounds__(256) void attn_fwd(
    const short* __restrict__ qbf, const short* __restrict__ kbf,
    const short* __restrict__ vtb, const int* __restrict__ am,
    short* __restrict__ ob)
{
  __shared__ __align__(16) short Ks[2][64*64];
  __shared__ __align__(16) short Vts[2][64*64];
  __shared__ __align__(16) short Ps[128*72];     // per-wave 32 rows, stride 144 B
  const int tid = threadIdx.x;
  const int lane = tid & 63, wid = tid >> 6;
  const int r16 = lane & 15, g = lane >> 4;
  const int bh = blockIdx.x;
  const int b = bh >> 4, h = bh & 15;
  const int grp = blockIdx.y >> 2, rem = blockIdx.y & 3;
  const int qi = (grp == 0) ? 15 - rem : (grp == 1) ? rem : (grp == 2) ? 11 - rem : 4 + rem;
  const int q0 = qi * 128;
  const int wq0 = q0 + wid * 32;

  // Q fragments (B-operand of swapped QK^T): q-col = r16, k = g*8+e
  bf16x8 qf[2][2];
#pragma unroll
  for (int m = 0; m < 2; ++m) {
    const short* qbase = qbf + ((size_t)bh*Tt + wq0 + m*16 + r16)*DHd;
    qf[m][0] = *reinterpret_cast<const bf16x8*>(qbase + g*8);
    qf[m][1] = *reinterpret_cast<const bf16x8*>(qbase + 32 + g*8);
  }

  f32x4 o[2][4];
  float mrow[2], lrow[2];
#pragma unroll
  for (int m = 0; m < 2; ++m) {
    mrow[m] = -INFINITY; lrow[m] = 0.f;
#pragma unroll
    for (int i = 0; i < 4; ++i) o[m][i] = (f32x4)0.0f;
  }

  char* Pw = (char*)Ps + (wid*32 + r16)*144;   // + m*2304 per m-half
  const int nkv = 2*qi + 2;

  const int srow = tid >> 3, scc = tid & 7;
  bf16x8 kr[2], vr[2];
#pragma unroll
  for (int c = 0; c < 2; ++c) {
    const int row = srow + c*32;
    kr[c] = *reinterpret_cast<const bf16x8*>(kbf + ((size_t)bh*Tt + row)*DHd + scc*8);
    vr[c] = *reinterpret_cast<const bf16x8*>(vtb + ((size_t)bh*DHd + row)*Tt + scc*8);
  }
#pragma unroll
  for (int c = 0; c < 2; ++c) {
    const int row = srow + c*32;
    const int off = (row*128 + scc*16) ^ ((row & 7) << 4);
    *reinterpret_cast<bf16x8*>((char*)Ks[0] + off) = kr[c];
    *reinterpret_cast<bf16x8*>((char*)Vts[0] + off) = vr[c];
  }
  __syncthreads();

  for (int kv = 0; kv < nkv; ++kv) {
    const int cur = kv & 1;
    const int kv0 = kv * 64;
    const unsigned long long mb = __ballot(am[b*Tt + kv0 + lane] != 0);
    if (kv + 1 < nkv) {       // issue next-tile loads early
#pragma unroll
      for (int c = 0; c < 2; ++c) {
        const int row = srow + c*32;
        kr[c] = *reinterpret_cast<const bf16x8*>(kbf + ((size_t)bh*Tt + kv0 + 64 + row)*DHd + scc*8);
        vr[c] = *reinterpret_cast<const bf16x8*>(vtb + ((size_t)bh*DHd + row)*Tt + kv0 + 64 + scc*8);
      }
    }

    if (kv0 <= wq0 + 31) {    // skip fully-above-diagonal tiles (wave-uniform)
      const char* kbp = (const char*)Ks[cur];
      const char* vbp = (const char*)Vts[cur];
      const int swzr = (r16 & 7) << 4;

      // ---- S^T = K · Q^T ----
      f32x4 st[2][4];
      __builtin_amdgcn_s_setprio(1);
#pragma unroll
      for (int kt = 0; kt < 4; ++kt) {
        const int rb = (kt*16 + r16)*128;
        const bf16x8 ka0 = *reinterpret_cast<const bf16x8*>(kbp + ((rb + g*16) ^ swzr));
        const bf16x8 ka1 = *reinterpret_cast<const bf16x8*>(kbp + ((rb + 64 + g*16) ^ swzr));
#pragma unroll
        for (int m = 0; m < 2; ++m) {
          f32x4 t = (f32x4)0.0f;
          t = __builtin_amdgcn_mfma_f32_16x16x32_bf16(ka0, qf[m][0], t, 0, 0, 0);
          t = __builtin_amdgcn_mfma_f32_16x16x32_bf16(ka1, qf[m][1], t, 0, 0, 0);
          st[m][kt] = t;
        }
      }
      __builtin_amdgcn_s_setprio(0);

      // ---- masking (wave-uniform branch; usually skipped) ----
      const bool notall = (mb != ~0ull);
      const bool diag = (kv0 + 63 > wq0);
      if (diag || notall) {
#pragma unroll
        for (int m = 0; m < 2; ++m) {
          const int qrow = wq0 + m*16 + r16;
#pragma unroll
          for (int kt = 0; kt < 4; ++kt)
#pragma unroll
            for (int r = 0; r < 4; ++r) {
              const int kl = kt*16 + g*4 + r;
              bool ok = !diag || (kv0 + kl <= qrow);
              if (notall) ok = ok && ((mb >> kl) & 1ull);
              if (!ok) st[m][kt][r] = -3.0e38f;
            }
        }
      }

      // ---- in-register online softmax + defer-rescale (THR=8) ----
      float mx[2], rs[2];
#pragma unroll
      for (int m = 0; m < 2; ++m) {
        f32x4 t0, t1;
#pragma unroll
        for (int i = 0; i < 4; ++i) { t0[i] = fmaxf(st[m][0][i], st[m][1][i]); t1[i] = fmaxf(st[m][2][i], st[m][3][i]); }
#pragma unroll
        for (int i = 0; i < 4; ++i) t0[i] = fmaxf(t0[i], t1[i]);
        mx[m] = fmaxf(fmaxf(t0[0], t0[1]), fmaxf(t0[2], t0[3]));
      }
      {
        float a0 = __shfl_xor(mx[0], 16), a1 = __shfl_xor(mx[1], 16);
        mx[0] = fmaxf(mx[0], a0); mx[1] = fmaxf(mx[1], a1);
        a0 = __shfl_xor(mx[0], 32); a1 = __shfl_xor(mx[1], 32);
        mx[0] = fmaxf(mx[0], a0); mx[1] = fmaxf(mx[1], a1);
      }
      const bool need = __any((mx[0] > mrow[0] + 8.f) || (mx[1] > mrow[1] + 8.f));
      if (need) {
#pragma unroll
        for (int m = 0; m < 2; ++m) {
          const float mnew = fmaxf(mrow[m], mx[m]);
          const float alpha = __builtin_amdgcn_exp2f(mrow[m] - mnew);
          mrow[m] = mnew;
          lrow[m] *= alpha;
#pragma unroll
          for (int dt = 0; dt < 4; ++dt) o[m][dt] *= alpha;
        }
      }

#pragma unroll
      for (int m = 0; m < 2; ++m) {
#pragma unroll
        for (int kt = 0; kt < 4; ++kt)
#pragma unroll
          for (int r = 0; r < 4; ++r)
            st[m][kt][r] = __builtin_amdgcn_exp2f(st[m][kt][r] - mrow[m]);
        char* pw = Pw + m*2304;
#pragma unroll
        for (int kt = 0; kt < 4; ++kt) {
          u32x2 w;
          w.x = cvtpk(st[m][kt][0], st[m][kt][1]);
          w.y = cvtpk(st[m][kt][2], st[m][kt][3]);
          *reinterpret_cast<u32x2*>(pw + kt*32 + g*8) = w;
        }
        f32x4 s4;
#pragma unroll
        for (int i = 0; i < 4; ++i) s4[i] = st[m][0][i] + st[m][1][i] + st[m][2][i] + st[m][3][i];
        rs[m] = (s4[0] + s4[1]) + (s4[2] + s4[3]);
      }
      {
        float a0 = __shfl_xor(rs[0], 16), a1 = __shfl_xor(rs[1], 16);
        rs[0] += a0; rs[1] += a1;
        a0 = __shfl_xor(rs[0], 32); a1 = __shfl_xor(rs[1], 32);
        rs[0] += a0; rs[1] += a1;
      }
      lrow[0] += rs[0]; lrow[1] += rs[1];

      __builtin_amdgcn_sched_barrier(0);

      // ---- O^T += Vt · P^T ----
      __builtin_amdgcn_s_setprio(1);
#pragma unroll
      for (int ks = 0; ks < 2; ++ks) {
        const bf16x8 pb0 = *reinterpret_cast<const bf16x8*>(Pw + ks*64 + g*16);
        const bf16x8 pb1 = *reinterpret_cast<const bf16x8*>(Pw + 2304 + ks*64 + g*16);
#pragma unroll
        for (int dt = 0; dt < 4; ++dt) {
          const int rb = (dt*16 + r16)*128;
          const bf16x8 va = *reinterpret_cast<const bf16x8*>(vbp + ((rb + ks*64 + g*16) ^ swzr));
          o[0][dt] = __builtin_amdgcn_mfma_f32_16x16x32_bf16(va, pb0, o[0][dt], 0, 0, 0);
          o[1][dt] = __builtin_amdgcn_mfma_f32_16x16x32_bf16(va, pb1, o[1][dt], 0, 0, 0);
        }
      }
      __builtin_amdgcn_s_setprio(0);
    }

    if (kv + 1 < nkv) {
#pragma unroll
      for (int c = 0; c < 2; ++c) {
        const int row = srow + c*32;
        const int off = (row*128 + scc*16) ^ ((row & 7) << 4);
        *reinterpret_cast<bf16x8*>((char*)Ks[cur^1] + off) = kr[c];
        *reinterpret_cast<bf16x8*>((char*)Vts[cur^1] + off) = vr[c];
      }
    }
    // single barrier: all waves done with buf[cur] reads (this iter) and
    // buf[cur^1] writes (above) before anyone proceeds.
    __syncthreads();
  }

  // ---- normalize + store O (lane holds q=r16, d=dt*16+g*4+r contiguous) ----
#pragma unroll
  for (int m = 0; m < 2; ++m) {
    const float inv = (mrow[m] > -1e37f) ? 1.0f / lrow[m] : 0.f;
    short* obase = ob + ((size_t)(b*Tt + wq0 + m*16 + r16))*Cc + h*DHd;
#pragma unroll
    for (int dt = 0; dt < 4; ++dt) {
      u32x2 w;
      w.x = cvtpk(o[m][dt][0]*inv, o[m][dt][1]*inv);
      w.y = cvtpk(o[m][dt][2]*inv, o[m][dt][3]*inv);
      *reinterpret_cast<u32x2*>(obase + dt*16 + g*4) = w;
    }
  }
}

// ---------------- launcher ----------------
extern "C" void kernel_launch(void* const* d_in, const int* in_sizes, int n_in,
                              void* d_out, int out_size, void* d_ws, size_t ws_size,
                              hipStream_t stream) {
  const float* x    = (const float*)d_in[0];
  const int*   am   = (const int*)d_in[1];
  const float* wqkv = (const float*)d_in[2];
  const float* wout = (const float*)d_in[3];
  float* out = (float*)d_out;

  const size_t mc = (size_t)Mm * Cc;        // 8,388,608
  short* ws    = (short*)d_ws;
  short* xb    = ws;                        // [8192,1024] bf16
  short* wqkvb = xb + mc;                   // [3072,1024]
  short* woutb = wqkvb + (size_t)3*Cc*Cc;   // [1024,1024]
  short* qbuf  = woutb + (size_t)Cc*Cc;     // [B,H,T,64] (pre-scaled by log2e/8)
  short* kbuf  = qbuf + mc;                 // [B,H,T,64]
  short* vtbuf = kbuf + mc;                 // [B,H,64,T] (transposed V)
  short* attnb = xb;                        // reuse x buffer after QKV GEMM

  cvt_bf16<<<(int)((mc/4 + 255)/256), 256, 0, stream>>>(x, xb, (int)(mc/4));
  cvt_bf16<<<(3*Cc*Cc/4 + 255)/256, 256, 0, stream>>>(wqkv, wqkvb, 3*Cc*Cc/4);
  cvt_bf16<<<(Cc*Cc/4 + 255)/256, 256, 0, stream>>>(wout, woutb, Cc*Cc/4);

  gemm_bt<0><<<dim3(3*Cc/128, Mm/128), 256, 0, stream>>>(
      xb, wqkvb, Cc, 3*Cc, nullptr, qbuf, kbuf, vtbuf);

  attn_fwd<<<dim3(Bb*Hh, Tt/128), 256, 0, stream>>>(qbuf, kbuf, vtbuf, am, attnb);

  gemm_bt<1><<<dim3(Cc/128, Mm/128), 256, 0, stream>>>(
      attnb, woutb, Cc, Cc, out, nullptr, nullptr, nullptr);
}

// Round 7
// 218.281 us; speedup vs baseline: 1.8837x; 1.0253x over previous
//
#include <hip/hip_runtime.h>
#include <cstdint>
#include <cmath>

// Causal self-attention: x[B,T,C] -> QKV proj -> flash attn -> out proj.
// B=4 T=2048 C=1024 H=16 DH=64. All matmuls in bf16 MFMA, fp32 accumulate.

#define Bb 4
#define Tt 2048
#define Cc 1024
#define Hh 16
#define DHd 64
#define Mm (Bb*Tt)   // 8192

typedef __attribute__((ext_vector_type(8))) short bf16x8;
typedef __attribute__((ext_vector_type(4))) short s16x4;
typedef __attribute__((ext_vector_type(4))) float f32x4;
typedef __attribute__((ext_vector_type(2))) unsigned int u32x2;

__device__ __forceinline__ short f2bf(float f) {
  uint32_t u = __builtin_bit_cast(uint32_t, f);
  u = (u + 0x7fffu + ((u >> 16) & 1u)) >> 16;   // RNE
  return (short)(uint16_t)u;
}

__device__ __forceinline__ uint32_t cvtpk(float lo, float hi) {
  uint32_t r;
  asm("v_cvt_pk_bf16_f32 %0, %1, %2" : "=v"(r) : "v"(lo), "v"(hi));
  return r;
}

// K=16 bf16 MFMA (P stays in registers as the B operand)
__device__ __forceinline__ f32x4 mfma16(s16x4 a, s16x4 b, f32x4 c) {
#if __has_builtin(__builtin_amdgcn_mfma_f32_16x16x16_bf16)
  return __builtin_amdgcn_mfma_f32_16x16x16_bf16(a, b, c, 0, 0, 0);
#elif __has_builtin(__builtin_amdgcn_mfma_f32_16x16x16bf16_1k)
  return __builtin_amdgcn_mfma_f32_16x16x16bf16_1k(a, b, c, 0, 0, 0);
#else
  f32x4 d;
  asm("v_mfma_f32_16x16x16_bf16 %0, %1, %2, %3" : "=v"(d) : "v"(a), "v"(b), "v"(c));
  return d;
#endif
}

// ---------------- fp32 -> bf16 convert (x4 vectorized) ----------------
__global__ void cvt_bf16(const float* __restrict__ in, short* __restrict__ out, int n4) {
  int i = blockIdx.x * blockDim.x + threadIdx.x;
  if (i >= n4) return;
  f32x4 v = reinterpret_cast<const f32x4*>(in)[i];
  s16x4 o;
  o.x = f2bf(v.x); o.y = f2bf(v.y); o.z = f2bf(v.z); o.w = f2bf(v.w);
  reinterpret_cast<s16x4*>(out)[i] = o;
}

// ---------------- 128x128 bf16 GEMM, C = A * Bt^T (both K-contiguous) ----------------
// MODE 0: QKV epilogue -> scatter to q [B,H,T,64] (scaled log2e/8), k [B,H,T,64],
//         and V TRANSPOSED vt [B,H,64,T] (packed b64 stores along t)
// MODE 1: plain fp32 store to Cout [M,N]
#define BK 32

template<int MODE>
__global__ __launch_bounds__(256) void gemm_bt(
    const short* __restrict__ A, const short* __restrict__ Bt, int K, int N,
    float* __restrict__ Cout,
    short* __restrict__ qb, short* __restrict__ kb, short* __restrict__ vtb)
{
  __shared__ __align__(16) short As[128*BK];
  __shared__ __align__(16) short Bs[128*BK];
  const int tid = threadIdx.x;
  const int lane = tid & 63, wid = tid >> 6;
  const int wr = wid >> 1, wc = wid & 1;
  const int bm = blockIdx.y, bn = blockIdx.x;
  const int r16 = lane & 15, g = lane >> 4;

  f32x4 acc[4][4];
#pragma unroll
  for (int i = 0; i < 4; ++i)
#pragma unroll
    for (int j = 0; j < 4; ++j) acc[i][j] = (f32x4)0.0f;

  const int srow = lane >> 2;
  const int scol = (lane & 3) * 8;
  const int ch0 = wid * 2;

  const int nk = K / BK;
  for (int kt = 0; kt < nk; ++kt) {
    const int k0 = kt * BK;
#pragma unroll
    for (int c = 0; c < 2; ++c) {
      const int chunk = ch0 + c;
      const int row = chunk * 16 + srow;
      const short* ga = A  + (size_t)(bm*128 + row)*K + k0 + scol;
      const short* gb = Bt + (size_t)(bn*128 + row)*K + k0 + scol;
      __builtin_amdgcn_global_load_lds((const __attribute__((address_space(1))) void*)ga,
                                       (__attribute__((address_space(3))) void*)(&As[chunk*512]), 16, 0, 0);
      __builtin_amdgcn_global_load_lds((const __attribute__((address_space(1))) void*)gb,
                                       (__attribute__((address_space(3))) void*)(&Bs[chunk*512]), 16, 0, 0);
    }
    __syncthreads();

    bf16x8 af[4], bfv[4];
#pragma unroll
    for (int mi = 0; mi < 4; ++mi)
      af[mi] = *reinterpret_cast<const bf16x8*>(&As[(wr*64 + mi*16 + r16)*BK + g*8]);
#pragma unroll
    for (int ni = 0; ni < 4; ++ni)
      bfv[ni] = *reinterpret_cast<const bf16x8*>(&Bs[(wc*64 + ni*16 + r16)*BK + g*8]);
#pragma unroll
    for (int mi = 0; mi < 4; ++mi)
#pragma unroll
      for (int ni = 0; ni < 4; ++ni)
        acc[mi][ni] = __builtin_amdgcn_mfma_f32_16x16x32_bf16(af[mi], bfv[ni], acc[mi][ni], 0, 0, 0);
    __syncthreads();
  }

  // epilogue: D layout col = lane&15, row = (lane>>4)*4 + r
#pragma unroll
  for (int mi = 0; mi < 4; ++mi) {
    const int row0 = bm*128 + wr*64 + mi*16 + g*4;
#pragma unroll
    for (int ni = 0; ni < 4; ++ni) {
      const int col_g = bn*128 + wc*64 + ni*16 + r16;
      if (MODE == 1) {
#pragma unroll
        for (int r = 0; r < 4; ++r)
          Cout[(size_t)(row0 + r) * N + col_g] = acc[mi][ni][r];
      } else {
        const int which = col_g >> 10;          // 0=q 1=k 2=v
        const int hd = col_g & 1023;
        const int h = hd >> 6, d = hd & 63;
        const int b = row0 >> 11, t0 = row0 & 2047;
        const int bh = b*Hh + h;
        if (which == 0) {
#pragma unroll
          for (int r = 0; r < 4; ++r)
            qb[(((size_t)bh*Tt + t0 + r) << 6) + d] = f2bf(acc[mi][ni][r] * 0.18033688f); // log2e/8
        } else if (which == 1) {
#pragma unroll
          for (int r = 0; r < 4; ++r)
            kb[(((size_t)bh*Tt + t0 + r) << 6) + d] = f2bf(acc[mi][ni][r]);
        } else {
          // transposed V: t contiguous along register index -> one packed b64 store
          u32x2 w;
          w.x = cvtpk(acc[mi][ni][0], acc[mi][ni][1]);
          w.y = cvtpk(acc[mi][ni][2], acc[mi][ni][3]);
          *reinterpret_cast<u32x2*>(vtb + ((size_t)bh*DHd + d)*Tt + t0) = w;
        }
      }
    }
  }
}

// ---------------- flash attention, causal + key mask ----------------
// flat grid 1024 blocks, XCD-clustered: xcd=lin&7 owns bh in [8*xcd, 8*xcd+8)
// (K/V working set 8*512KB = 4MB = one L2). 4 waves * 32 q rows.
// Swapped QK^T (S^T = K·Q^T, 16x16x32) -> in-register softmax ->
// PV via 16x16x16 MFMA with P consumed DIRECTLY from registers (no P LDS).
// K/V double-buffered, XOR-swizzled stride-64 LDS; 1 barrier/tile.
__global__ __launch_bounds__(256) void attn_fwd(
    const short* __restrict__ qbf, const short* __restrict__ kbf,
    const short* __restrict__ vtb, const int* __restrict__ am,
    short* __restrict__ ob)
{
  __shared__ __align__(16) short Ks[2][64*64];
  __shared__ __align__(16) short Vts[2][64*64];
  const int tid = threadIdx.x;
  const int lane = tid & 63, wid = tid >> 6;
  const int r16 = lane & 15, g = lane >> 4;

  // XCD-clustered, heavy-first balanced mapping
  const int lin = blockIdx.x;
  const int xcd = lin & 7;
  const int idx = lin >> 3;              // 0..127
  const int bh  = xcd * 8 + (idx & 7);
  const int qi_raw = idx >> 3;           // 0..15, dispatch order
  const int grp = qi_raw >> 2, rem = qi_raw & 3;
  const int qi = (grp == 0) ? 15 - rem : (grp == 1) ? rem : (grp == 2) ? 11 - rem : 4 + rem;
  const int b = bh >> 4, h = bh & 15;
  const int q0 = qi * 128;
  const int wq0 = q0 + wid * 32;

  // Q fragments (B-operand of swapped QK^T): q-col = r16, k = g*8+e
  bf16x8 qf[2][2];
#pragma unroll
  for (int m = 0; m < 2; ++m) {
    const short* qbase = qbf + ((size_t)bh*Tt + wq0 + m*16 + r16)*DHd;
    qf[m][0] = *reinterpret_cast<const bf16x8*>(qbase + g*8);
    qf[m][1] = *reinterpret_cast<const bf16x8*>(qbase + 32 + g*8);
  }

  f32x4 o[2][4];
  float mrow[2], lrow[2];
#pragma unroll
  for (int m = 0; m < 2; ++m) {
    mrow[m] = -INFINITY; lrow[m] = 0.f;
#pragma unroll
    for (int i = 0; i < 4; ++i) o[m][i] = (f32x4)0.0f;
  }

  const int nkv = 2*qi + 2;
  const int srow = tid >> 3, scc = tid & 7;
  bf16x8 kr[2], vr[2];
#pragma unroll
  for (int c = 0; c < 2; ++c) {
    const int row = srow + c*32;
    kr[c] = *reinterpret_cast<const bf16x8*>(kbf + ((size_t)bh*Tt + row)*DHd + scc*8);
    vr[c] = *reinterpret_cast<const bf16x8*>(vtb + ((size_t)bh*DHd + row)*Tt + scc*8);
  }
#pragma unroll
  for (int c = 0; c < 2; ++c) {
    const int row = srow + c*32;
    const int off = (row*128 + scc*16) ^ ((row & 7) << 4);
    *reinterpret_cast<bf16x8*>((char*)Ks[0] + off) = kr[c];
    *reinterpret_cast<bf16x8*>((char*)Vts[0] + off) = vr[c];
  }
  __syncthreads();

  for (int kv = 0; kv < nkv; ++kv) {
    const int cur = kv & 1;
    const int kv0 = kv * 64;
    const unsigned long long mb = __ballot(am[b*Tt + kv0 + lane] != 0);
    if (kv + 1 < nkv) {       // issue next-tile loads early
#pragma unroll
      for (int c = 0; c < 2; ++c) {
        const int row = srow + c*32;
        kr[c] = *reinterpret_cast<const bf16x8*>(kbf + ((size_t)bh*Tt + kv0 + 64 + row)*DHd + scc*8);
        vr[c] = *reinterpret_cast<const bf16x8*>(vtb + ((size_t)bh*DHd + row)*Tt + kv0 + 64 + scc*8);
      }
    }

    if (kv0 <= wq0 + 31) {    // skip fully-above-diagonal tiles (wave-uniform)
      const char* kbp = (const char*)Ks[cur];
      const char* vbp = (const char*)Vts[cur];
      const int swzr = (r16 & 7) << 4;

      // ---- S^T = K · Q^T (16x16x32) ----
      f32x4 st[2][4];
      __builtin_amdgcn_s_setprio(1);
#pragma unroll
      for (int kt = 0; kt < 4; ++kt) {
        const int rb = (kt*16 + r16)*128;
        const bf16x8 ka0 = *reinterpret_cast<const bf16x8*>(kbp + ((rb + g*16) ^ swzr));
        const bf16x8 ka1 = *reinterpret_cast<const bf16x8*>(kbp + ((rb + 64 + g*16) ^ swzr));
#pragma unroll
        for (int m = 0; m < 2; ++m) {
          f32x4 t = (f32x4)0.0f;
          t = __builtin_amdgcn_mfma_f32_16x16x32_bf16(ka0, qf[m][0], t, 0, 0, 0);
          t = __builtin_amdgcn_mfma_f32_16x16x32_bf16(ka1, qf[m][1], t, 0, 0, 0);
          st[m][kt] = t;
        }
      }
      __builtin_amdgcn_s_setprio(0);

      // ---- masking (wave-uniform branch; usually skipped) ----
      const bool notall = (mb != ~0ull);
      const bool diag = (kv0 + 63 > wq0);
      if (diag || notall) {
#pragma unroll
        for (int m = 0; m < 2; ++m) {
          const int qrow = wq0 + m*16 + r16;
#pragma unroll
          for (int kt = 0; kt < 4; ++kt)
#pragma unroll
            for (int r = 0; r < 4; ++r) {
              const int kl = kt*16 + g*4 + r;
              bool ok = !diag || (kv0 + kl <= qrow);
              if (notall) ok = ok && ((mb >> kl) & 1ull);
              if (!ok) st[m][kt][r] = -3.0e38f;
            }
        }
      }

      // ---- in-register online softmax + defer-rescale (THR=8, log2 domain) ----
      float mx[2], rs[2];
#pragma unroll
      for (int m = 0; m < 2; ++m) {
        f32x4 t0, t1;
#pragma unroll
        for (int i = 0; i < 4; ++i) { t0[i] = fmaxf(st[m][0][i], st[m][1][i]); t1[i] = fmaxf(st[m][2][i], st[m][3][i]); }
#pragma unroll
        for (int i = 0; i < 4; ++i) t0[i] = fmaxf(t0[i], t1[i]);
        mx[m] = fmaxf(fmaxf(t0[0], t0[1]), fmaxf(t0[2], t0[3]));
      }
      {
        float a0 = __shfl_xor(mx[0], 16), a1 = __shfl_xor(mx[1], 16);
        mx[0] = fmaxf(mx[0], a0); mx[1] = fmaxf(mx[1], a1);
        a0 = __shfl_xor(mx[0], 32); a1 = __shfl_xor(mx[1], 32);
        mx[0] = fmaxf(mx[0], a0); mx[1] = fmaxf(mx[1], a1);
      }
      const bool need = __any((mx[0] > mrow[0] + 8.f) || (mx[1] > mrow[1] + 8.f));
      if (need) {
#pragma unroll
        for (int m = 0; m < 2; ++m) {
          const float mnew = fmaxf(mrow[m], mx[m]);
          const float alpha = __builtin_amdgcn_exp2f(mrow[m] - mnew);
          mrow[m] = mnew;
          lrow[m] *= alpha;
#pragma unroll
          for (int dt = 0; dt < 4; ++dt) o[m][dt] *= alpha;
        }
      }

      // exp + pack P into registers (B-frags of 16x16x16: k = g*4+e per kt)
      s16x4 pb[2][4];
#pragma unroll
      for (int m = 0; m < 2; ++m) {
#pragma unroll
        for (int kt = 0; kt < 4; ++kt)
#pragma unroll
          for (int r = 0; r < 4; ++r)
            st[m][kt][r] = __builtin_amdgcn_exp2f(st[m][kt][r] - mrow[m]);
#pragma unroll
        for (int kt = 0; kt < 4; ++kt) {
          u32x2 w;
          w.x = cvtpk(st[m][kt][0], st[m][kt][1]);
          w.y = cvtpk(st[m][kt][2], st[m][kt][3]);
          pb[m][kt] = __builtin_bit_cast(s16x4, w);
        }
        f32x4 s4;
#pragma unroll
        for (int i = 0; i < 4; ++i) s4[i] = st[m][0][i] + st[m][1][i] + st[m][2][i] + st[m][3][i];
        rs[m] = (s4[0] + s4[1]) + (s4[2] + s4[3]);
      }
      {
        float a0 = __shfl_xor(rs[0], 16), a1 = __shfl_xor(rs[1], 16);
        rs[0] += a0; rs[1] += a1;
        a0 = __shfl_xor(rs[0], 32); a1 = __shfl_xor(rs[1], 32);
        rs[0] += a0; rs[1] += a1;
      }
      lrow[0] += rs[0]; lrow[1] += rs[1];

      // ---- O^T += Vt · P^T : 16x16x16 MFMA, P direct from registers ----
      __builtin_amdgcn_s_setprio(1);
#pragma unroll
      for (int dt = 0; dt < 4; ++dt) {
        const int row = dt*16 + r16;
        const int rb = row*128;
        const int r7 = row & 7;
#pragma unroll
        for (int kt = 0; kt < 4; ++kt) {
          const s16x4 va = *reinterpret_cast<const s16x4*>(
              vbp + rb + ((((kt<<1) + (g>>1)) ^ r7) << 4) + (g & 1)*8);
          o[0][dt] = mfma16(va, pb[0][kt], o[0][dt]);
          o[1][dt] = mfma16(va, pb[1][kt], o[1][dt]);
        }
      }
      __builtin_amdgcn_s_setprio(0);
    }

    if (kv + 1 < nkv) {
#pragma unroll
      for (int c = 0; c < 2; ++c) {
        const int row = srow + c*32;
        const int off = (row*128 + scc*16) ^ ((row & 7) << 4);
        *reinterpret_cast<bf16x8*>((char*)Ks[cur^1] + off) = kr[c];
        *reinterpret_cast<bf16x8*>((char*)Vts[cur^1] + off) = vr[c];
      }
    }
    // single barrier: buf[cur] reads done and buf[cur^1] writes visible
    __syncthreads();
  }

  // ---- normalize + store O (lane holds q=r16, d=dt*16+g*4+r contiguous) ----
#pragma unroll
  for (int m = 0; m < 2; ++m) {
    const float inv = (mrow[m] > -1e37f) ? 1.0f / lrow[m] : 0.f;
    short* obase = ob + ((size_t)(b*Tt + wq0 + m*16 + r16))*Cc + h*DHd;
#pragma unroll
    for (int dt = 0; dt < 4; ++dt) {
      u32x2 w;
      w.x = cvtpk(o[m][dt][0]*inv, o[m][dt][1]*inv);
      w.y = cvtpk(o[m][dt][2]*inv, o[m][dt][3]*inv);
      *reinterpret_cast<u32x2*>(obase + dt*16 + g*4) = w;
    }
  }
}

// ---------------- launcher ----------------
extern "C" void kernel_launch(void* const* d_in, const int* in_sizes, int n_in,
                              void* d_out, int out_size, void* d_ws, size_t ws_size,
                              hipStream_t stream) {
  const float* x    = (const float*)d_in[0];
  const int*   am   = (const int*)d_in[1];
  const float* wqkv = (const float*)d_in[2];
  const float* wout = (const float*)d_in[3];
  float* out = (float*)d_out;

  const size_t mc = (size_t)Mm * Cc;        // 8,388,608
  short* ws    = (short*)d_ws;
  short* xb    = ws;                        // [8192,1024] bf16
  short* wqkvb = xb + mc;                   // [3072,1024]
  short* woutb = wqkvb + (size_t)3*Cc*Cc;   // [1024,1024]
  short* qbuf  = woutb + (size_t)Cc*Cc;     // [B,H,T,64] (pre-scaled by log2e/8)
  short* kbuf  = qbuf + mc;                 // [B,H,T,64]
  short* vtbuf = kbuf + mc;                 // [B,H,64,T] (transposed V)
  short* attnb = xb;                        // reuse x buffer after QKV GEMM

  cvt_bf16<<<(int)((mc/4 + 255)/256), 256, 0, stream>>>(x, xb, (int)(mc/4));
  cvt_bf16<<<(3*Cc*Cc/4 + 255)/256, 256, 0, stream>>>(wqkv, wqkvb, 3*Cc*Cc/4);
  cvt_bf16<<<(Cc*Cc/4 + 255)/256, 256, 0, stream>>>(wout, woutb, Cc*Cc/4);

  gemm_bt<0><<<dim3(3*Cc/128, Mm/128), 256, 0, stream>>>(
      xb, wqkvb, Cc, 3*Cc, nullptr, qbuf, kbuf, vtbuf);

  attn_fwd<<<dim3(Bb*Hh*Tt/128), 256, 0, stream>>>(qbuf, kbuf, vtbuf, am, attnb);

  gemm_bt<1><<<dim3(Cc/128, Mm/128), 256, 0, stream>>>(
      attnb, woutb, Cc, Cc, out, nullptr, nullptr, nullptr);
}